// Round 9
// baseline (152.388 us; speedup 1.0000x reference)
//
#include <hip/hip_runtime.h>
#include <hip/hip_fp16.h>
#include <stdint.h>

typedef _Float16 f16;
typedef _Float16 half8  __attribute__((ext_vector_type(8)));
typedef _Float16 half4v __attribute__((ext_vector_type(4)));
typedef float    f32x4  __attribute__((ext_vector_type(4)));

#define NBATCH 4
#define SEQ    4096
#define DMODEL 256
#define DHEAD  64
#define NQKV   192

// ---------------------------------------------------------------------------
// Kernel A: qkv = x @ W_qkv + b_qkv (fp32 VALU). Emits:
//   qh[row][d]   fp16, pre-scaled by 1/8 (exact pow2)
//   kh[row][d]   fp16 row-major        (QK^T stages this)
//   vt[b][d][seq] fp16 transposed      (PV stages this d-major)
// ---------------------------------------------------------------------------
__global__ __launch_bounds__(256) void qkv_proj(
    const float* __restrict__ x, const float* __restrict__ Wq,
    const float* __restrict__ bq,
    f16* __restrict__ qh, f16* __restrict__ kh, f16* __restrict__ vt)
{
  __shared__ float xs[32][64];      // 8 KB
  __shared__ float wsh[64][NQKV];   // 48 KB
  const int t = threadIdx.x;
  const int row0 = blockIdx.x * 32;
  const int cg = t & 31;            // 32 col-groups x 6 cols
  const int rg = t >> 5;            // 8 row-groups x 4 rows
  const int n0 = cg * 6;
  const int m0 = rg * 4;
  float acc[4][6];
#pragma unroll
  for (int i = 0; i < 4; ++i)
#pragma unroll
    for (int j = 0; j < 6; ++j) acc[i][j] = 0.f;

  for (int kc = 0; kc < 4; ++kc) {
    const int k0 = kc * 64;
#pragma unroll
    for (int j = 0; j < 8; ++j) {
      int li = j * 256 + t;
      xs[li >> 6][li & 63] = x[(size_t)(row0 + (li >> 6)) * DMODEL + k0 + (li & 63)];
    }
#pragma unroll
    for (int j = 0; j < 48; ++j) {
      int li = j * 256 + t;
      int r = li / NQKV, c = li % NQKV;
      wsh[r][c] = Wq[(size_t)(k0 + r) * NQKV + c];
    }
    __syncthreads();
#pragma unroll
    for (int kk4 = 0; kk4 < 16; ++kk4) {
      float4 a4[4];
#pragma unroll
      for (int i = 0; i < 4; ++i) a4[i] = *(const float4*)&xs[m0 + i][kk4 * 4];
#pragma unroll
      for (int e = 0; e < 4; ++e) {
        const int kk = kk4 * 4 + e;
        float2 b01 = *(const float2*)&wsh[kk][n0];
        float2 b23 = *(const float2*)&wsh[kk][n0 + 2];
        float2 b45 = *(const float2*)&wsh[kk][n0 + 4];
#pragma unroll
        for (int i = 0; i < 4; ++i) {
          const float a = (e == 0) ? a4[i].x : (e == 1) ? a4[i].y : (e == 2) ? a4[i].z : a4[i].w;
          acc[i][0] = fmaf(a, b01.x, acc[i][0]);
          acc[i][1] = fmaf(a, b01.y, acc[i][1]);
          acc[i][2] = fmaf(a, b23.x, acc[i][2]);
          acc[i][3] = fmaf(a, b23.y, acc[i][3]);
          acc[i][4] = fmaf(a, b45.x, acc[i][4]);
          acc[i][5] = fmaf(a, b45.y, acc[i][5]);
        }
      }
    }
    __syncthreads();
  }
  const int bi  = row0 >> 12;           // batch
  const int seq0 = (row0 & (SEQ - 1)) + m0;
#pragma unroll
  for (int j = 0; j < 6; ++j) {
    const int n = n0 + j;
    const float b = bq[n];
    const float v0 = acc[0][j] + b, v1 = acc[1][j] + b;
    const float v2 = acc[2][j] + b, v3 = acc[3][j] + b;
    if (n < 64) {
      const size_t r = (size_t)row0 + m0;
      qh[(r + 0) * DHEAD + n] = (f16)(v0 * 0.125f);
      qh[(r + 1) * DHEAD + n] = (f16)(v1 * 0.125f);
      qh[(r + 2) * DHEAD + n] = (f16)(v2 * 0.125f);
      qh[(r + 3) * DHEAD + n] = (f16)(v3 * 0.125f);
    } else if (n < 128) {
      const size_t r = (size_t)row0 + m0;
      kh[(r + 0) * DHEAD + (n - 64)] = (f16)v0;
      kh[(r + 1) * DHEAD + (n - 64)] = (f16)v1;
      kh[(r + 2) * DHEAD + (n - 64)] = (f16)v2;
      kh[(r + 3) * DHEAD + (n - 64)] = (f16)v3;
    } else {
      half4v pk = {(f16)v0, (f16)v1, (f16)v2, (f16)v3};
      *(half4v*)(vt + (size_t)bi * DHEAD * SEQ + (size_t)(n - 128) * SEQ + seq0) = pk;
    }
  }
}

// ---------------------------------------------------------------------------
// Kernel B: fused scores -> threshold -> masked softmax -> PV.
// R7 verified async template (global_load_lds, dbuf, counted vmcnt(4),
// SCHED_PIN before in-loop stage issue). 32 q-rows per block: each wave
// computes TWO 16-row Q-tiles against the same staged K/V. R9 fix: epilogue
// reduce in TWO 16-row passes (R8's 32x68 red overflowed the 8 KB region).
// ---------------------------------------------------------------------------
#define WAVES  8
#define CHUNK  32
#define NCHUNK 16
#define BUFH   2048    // halves per buffer (4 KB = 32 rows x 64 halves)

__device__ __forceinline__ int khash(int row) {   // bijective per permuted tile
  return ((row >> 2) & 6) | ((row >> 1) & 1);
}

typedef __attribute__((address_space(3))) f16 as3_f16;
typedef __attribute__((address_space(1))) const f16 as1_f16;

__device__ __forceinline__ void gll16(const f16* g, f16* l) {
  __builtin_amdgcn_global_load_lds((as1_f16*)g, (as3_f16*)l, 16, 0, 0);
}

#define SCHED_PIN __builtin_amdgcn_sched_barrier(0)
#define WAITVM4 do { asm volatile("s_waitcnt vmcnt(4)" ::: "memory"); \
                     __builtin_amdgcn_sched_barrier(0); } while (0)
#define WAITVM0 do { asm volatile("s_waitcnt vmcnt(0)" ::: "memory"); \
                     __builtin_amdgcn_sched_barrier(0); } while (0)

// K chunk -> LDS[row 0..31][slot 0..7], source slot pre-XOR'd with khash(row)
__device__ __forceinline__ void stage_k(const f16* kchunk, f16* buf, int l) {
#pragma unroll
  for (int i = 0; i < 4; ++i) {
    const int row = i * 8 + (l >> 3);
    const int c8 = (l & 7) ^ khash(row);
    gll16(kchunk + row * DHEAD + c8 * 8, buf + i * 512);
  }
}

// V chunk -> LDS rows = d&31 (128 B), slots 0..3 = d<32, 4..7 = d>=32, XOR r&7
__device__ __forceinline__ void stage_v(const f16* vchunk, f16* buf, int l) {
#pragma unroll
  for (int i = 0; i < 4; ++i) {
    const int r = i * 8 + (l >> 3);
    const int jj = (l & 7) ^ (r & 7);
    const int d = ((jj >> 2) << 5) + r;
    const int kb = jj & 3;
    gll16(vchunk + (size_t)d * SEQ + kb * 8, buf + i * 512);
  }
}

__global__ __launch_bounds__(512, 2) void attn_fused(
    const f16* __restrict__ qh, const f16* __restrict__ kh,
    const f16* __restrict__ vt, float* __restrict__ attn_out)
{
  __shared__ f16 stage[WAVES][2 * BUFH];     // 64 KB: per-wave double buffer
  __shared__ float selbuf[2][WAVES][32];
  __shared__ float zrow[32];

  const int tid = threadIdx.x;
  const int w = tid >> 6;
  const int l = tid & 63;
  const int qr = l & 15;
  const int g  = l >> 4;
  const int bi = blockIdx.x >> 7;
  const int rb = blockIdx.x & 127;
  const size_t qrow0  = (size_t)bi * SEQ + (size_t)rb * 32;   // 32 q-rows/block
  const size_t kvbase = (size_t)bi * SEQ * DHEAD;
  const int key0 = w * (CHUNK * NCHUNK);

  f16* const mybuf = &stage[w][0];

  // Q fragments for both tiles (B operand), q pre-scaled by 1/8 in qh.
  half8 qfa0, qfa1, qfb0, qfb1;
  {
    const f16* qpa = qh + (qrow0 + qr) * DHEAD;
    qfa0 = *(const half8*)(qpa + 8 * g);
    qfa1 = *(const half8*)(qpa + 32 + 8 * g);
    const f16* qpb = qh + (qrow0 + 16 + qr) * DHEAD;
    qfb0 = *(const half8*)(qpb + 8 * g);
    qfb1 = *(const half8*)(qpb + 32 + 8 * g);
  }

  half4v Pa[2 * NCHUNK], Pb[2 * NCHUNK];  // P[2kc+kt][r] = S[q][32kc+8g+4kt+r]
  float mna = 1e30f, mxa = -1e30f, mnb = 1e30f, mxb = -1e30f;

  // ---- QK^T: async pipeline, no barriers ----
  const f16* kc0 = kh + kvbase + (size_t)key0 * DHEAD;
  stage_k(kc0, mybuf, l);
  stage_k(kc0 + 32 * DHEAD, mybuf + BUFH, l);
#pragma unroll
  for (int kc = 0; kc < NCHUNK; ++kc) {
    if (kc < NCHUNK - 1) { WAITVM4; } else { WAITVM0; }
    const f16* bufp = mybuf + (kc & 1) * BUFH;
#pragma unroll
    for (int kt = 0; kt < 2; ++kt) {
      const int rowk = 8 * (qr >> 2) + 4 * kt + (qr & 3);   // permuted key row
      const int h = khash(rowk);
      half8 kf0 = *(const half8*)(bufp + rowk * DHEAD + ((g ^ h) * 8));
      half8 kf1 = *(const half8*)(bufp + rowk * DHEAD + (((4 + g) ^ h) * 8));
      f32x4 ca = {0.f, 0.f, 0.f, 0.f};
      ca = __builtin_amdgcn_mfma_f32_16x16x32_f16(kf0, qfa0, ca, 0, 0, 0);
      ca = __builtin_amdgcn_mfma_f32_16x16x32_f16(kf1, qfa1, ca, 0, 0, 0);
      f32x4 cb = {0.f, 0.f, 0.f, 0.f};
      cb = __builtin_amdgcn_mfma_f32_16x16x32_f16(kf0, qfb0, cb, 0, 0, 0);
      cb = __builtin_amdgcn_mfma_f32_16x16x32_f16(kf1, qfb1, cb, 0, 0, 0);
      mna = fminf(mna, fminf(fminf(ca[0], ca[1]), fminf(ca[2], ca[3])));
      mxa = fmaxf(mxa, fmaxf(fmaxf(ca[0], ca[1]), fmaxf(ca[2], ca[3])));
      mnb = fminf(mnb, fminf(fminf(cb[0], cb[1]), fminf(cb[2], cb[3])));
      mxb = fmaxf(mxb, fmaxf(fmaxf(cb[0], cb[1]), fmaxf(cb[2], cb[3])));
      Pa[kc * 2 + kt] = (half4v){(f16)ca[0], (f16)ca[1], (f16)ca[2], (f16)ca[3]};
      Pb[kc * 2 + kt] = (half4v){(f16)cb[0], (f16)cb[1], (f16)cb[2], (f16)cb[3]};
    }
    if (kc + 2 < NCHUNK) {
      SCHED_PIN;   // all reads of buf[kc&1] complete (in-order DS) before DMA
      stage_k(kc0 + (size_t)(kc + 2) * 32 * DHEAD, mybuf + (kc & 1) * BUFH, l);
    }
  }

  // ---- per-row min/max across lanes and waves (both tiles) ----
  mna = fminf(mna, __shfl_xor(mna, 16, 64));
  mna = fminf(mna, __shfl_xor(mna, 32, 64));
  mxa = fmaxf(mxa, __shfl_xor(mxa, 16, 64));
  mxa = fmaxf(mxa, __shfl_xor(mxa, 32, 64));
  mnb = fminf(mnb, __shfl_xor(mnb, 16, 64));
  mnb = fminf(mnb, __shfl_xor(mnb, 32, 64));
  mxb = fmaxf(mxb, __shfl_xor(mxb, 16, 64));
  mxb = fmaxf(mxb, __shfl_xor(mxb, 32, 64));
  if (l < 16) {
    selbuf[0][w][qr] = mna;      selbuf[1][w][qr] = mxa;
    selbuf[0][w][16 + qr] = mnb; selbuf[1][w][16 + qr] = mxb;
  }
  __syncthreads();
  float loa = 1e30f, hia = -1e30f, lob = 1e30f, hib = -1e30f;
#pragma unroll
  for (int j = 0; j < WAVES; ++j) {
    loa = fminf(loa, selbuf[0][j][qr]);      hia = fmaxf(hia, selbuf[1][j][qr]);
    lob = fminf(lob, selbuf[0][j][16 + qr]); hib = fmaxf(hib, selbuf[1][j][16 + qr]);
  }
  __syncthreads();   // lo/hi reads done before iter 0 overwrites selbuf[0]

  // ---- bisection on sampled count (512 of 4096 per row; target 256) ----
#pragma unroll
  for (int it = 0; it < 8; ++it) {
    const float tma = 0.5f * (loa + hia);
    const float tmb = 0.5f * (lob + hib);
    const f16 tha = (f16)tma, thb = (f16)tmb;
    int ca = 0, cb = 0;
#pragma unroll
    for (int j = 0; j < 2 * NCHUNK; j += 8) {
      half4v sa = Pa[j], sb = Pb[j];
      ca += (sa[0] >= tha) + (sa[1] >= tha) + (sa[2] >= tha) + (sa[3] >= tha);
      cb += (sb[0] >= thb) + (sb[1] >= thb) + (sb[2] >= thb) + (sb[3] >= thb);
    }
    ca += __shfl_xor(ca, 16, 64); ca += __shfl_xor(ca, 32, 64);
    cb += __shfl_xor(cb, 16, 64); cb += __shfl_xor(cb, 32, 64);
    if (l < 16) {
      selbuf[it & 1][w][qr] = (float)ca;
      selbuf[it & 1][w][16 + qr] = (float)cb;
    }
    __syncthreads();
    float ta = 0.f, tb = 0.f;
#pragma unroll
    for (int j = 0; j < WAVES; ++j) {
      ta += selbuf[it & 1][j][qr];
      tb += selbuf[it & 1][j][16 + qr];
    }
    if (ta >= 256.f) loa = tma; else hia = tma;
    if (tb >= 256.f) lob = tmb; else hib = tmb;
  }
  const float thra = loa, thrb = lob;

  // ---- prefetch V chunks 0/1 (exp loop + z-barrier hide the latency) ----
  const f16* vchunk0 = vt + (size_t)bi * DHEAD * SEQ + key0;
  stage_v(vchunk0, mybuf, l);
  stage_v(vchunk0 + 32, mybuf + BUFH, l);

  // ---- exp in place (masked -> exp(0)=1, matches softmax(scores*mask)) ----
  float za = 0.f, zb = 0.f;
#pragma unroll
  for (int j = 0; j < 2 * NCHUNK; ++j) {
    half4v sa = Pa[j];
    float a0 = (float)sa[0], a1 = (float)sa[1], a2 = (float)sa[2], a3 = (float)sa[3];
    a0 = (a0 >= thra) ? __expf(a0) : 1.f;
    a1 = (a1 >= thra) ? __expf(a1) : 1.f;
    a2 = (a2 >= thra) ? __expf(a2) : 1.f;
    a3 = (a3 >= thra) ? __expf(a3) : 1.f;
    za += (a0 + a1) + (a2 + a3);
    Pa[j] = (half4v){(f16)a0, (f16)a1, (f16)a2, (f16)a3};
    half4v sb = Pb[j];
    float b0 = (float)sb[0], b1 = (float)sb[1], b2 = (float)sb[2], b3 = (float)sb[3];
    b0 = (b0 >= thrb) ? __expf(b0) : 1.f;
    b1 = (b1 >= thrb) ? __expf(b1) : 1.f;
    b2 = (b2 >= thrb) ? __expf(b2) : 1.f;
    b3 = (b3 >= thrb) ? __expf(b3) : 1.f;
    zb += (b0 + b1) + (b2 + b3);
    Pb[j] = (half4v){(f16)b0, (f16)b1, (f16)b2, (f16)b3};
  }
  za += __shfl_xor(za, 16, 64); za += __shfl_xor(za, 32, 64);
  zb += __shfl_xor(zb, 16, 64); zb += __shfl_xor(zb, 32, 64);
  if (l < 16) { selbuf[0][w][qr] = za; selbuf[0][w][16 + qr] = zb; }
  __syncthreads();
  if (w == 0 && l < 32) {
    float t2 = 0.f;
#pragma unroll
    for (int j = 0; j < WAVES; ++j) t2 += selbuf[0][j][l];
    zrow[l] = t2;   // consumed after the post-PV barrier
  }

  // ---- PV: O^T = V^T P^T; A = V^T (b128 LDS reads), B = P register concat ----
  f32x4 acca[4], accb[4];
#pragma unroll
  for (int p = 0; p < 4; ++p) {
    acca[p] = (f32x4){0.f, 0.f, 0.f, 0.f};
    accb[p] = (f32x4){0.f, 0.f, 0.f, 0.f};
  }

#pragma unroll
  for (int kc = 0; kc < NCHUNK; ++kc) {
    if (kc < NCHUNK - 1) { WAITVM4; } else { WAITVM0; }
    const f16* bufp = mybuf + (kc & 1) * BUFH;
    const half8 pba = __builtin_shufflevector(Pa[kc * 2], Pa[kc * 2 + 1],
                                              0, 1, 2, 3, 4, 5, 6, 7);
    const half8 pbb = __builtin_shufflevector(Pb[kc * 2], Pb[kc * 2 + 1],
                                              0, 1, 2, 3, 4, 5, 6, 7);
#pragma unroll
    for (int pnl = 0; pnl < 4; ++pnl) {
      const int d = 16 * pnl + qr;
      const int r = d & 31;
      const int j = (((d >> 5) << 2) + g) ^ (r & 7);
      half8 va = *(const half8*)(bufp + r * 64 + j * 8);
      acca[pnl] = __builtin_amdgcn_mfma_f32_16x16x32_f16(va, pba, acca[pnl], 0, 0, 0);
      accb[pnl] = __builtin_amdgcn_mfma_f32_16x16x32_f16(va, pbb, accb[pnl], 0, 0, 0);
    }
    if (kc + 2 < NCHUNK) {
      SCHED_PIN;   // all reads of buf[kc&1] complete (in-order DS) before DMA
      stage_v(vchunk0 + (kc + 2) * 32, mybuf + (kc & 1) * BUFH, l);
    }
  }

  // ---- cross-wave reduce + divide by Z: TWO 16-row passes so the 68-pad
  // red (16x68x4 = 4352 B) fits the 8 KB wave region (R8 overflow fix) ----
  float* red = (float*)mybuf;
#pragma unroll
  for (int pnl = 0; pnl < 4; ++pnl)
    *(f32x4*)&red[qr * 68 + pnl * 16 + 4 * g] = acca[pnl];
  __syncthreads();
#pragma unroll
  for (int oo = 0; oo < 2; ++oo) {
    const int o = tid * 2 + oo;
    const int i = o >> 6, n = o & 63;
    float s = 0.f;
#pragma unroll
    for (int j = 0; j < WAVES; ++j) s += ((const float*)&stage[j][0])[i * 68 + n];
    attn_out[(qrow0 + i) * DHEAD + n] = s / zrow[i];
  }
  __syncthreads();   // pass-a reads complete before pass-b overwrites red
#pragma unroll
  for (int pnl = 0; pnl < 4; ++pnl)
    *(f32x4*)&red[qr * 68 + pnl * 16 + 4 * g] = accb[pnl];
  __syncthreads();
#pragma unroll
  for (int oo = 0; oo < 2; ++oo) {
    const int o = tid * 2 + oo;
    const int i = o >> 6, n = o & 63;
    float s = 0.f;
#pragma unroll
    for (int j = 0; j < WAVES; ++j) s += ((const float*)&stage[j][0])[i * 68 + n];
    attn_out[(qrow0 + 16 + i) * DHEAD + n] = s / zrow[16 + i];
  }
}

// ---------------------------------------------------------------------------
// Kernel C: out = attn_out @ W_out + b_out (fp32). 32 rows x 256 cols per WG.
// ---------------------------------------------------------------------------
__global__ __launch_bounds__(256) void out_proj(
    const float* __restrict__ attn, const float* __restrict__ Wo,
    const float* __restrict__ bo, float* __restrict__ out)
{
  __shared__ float wl[32][DMODEL];  // 32 KB
  __shared__ float at[32][DHEAD];   // 8 KB
  const int t = threadIdx.x;
  const int row0 = blockIdx.x * 32;
  const int rg = t >> 6;
  const int cg = t & 63;
  float acc[8][4];
#pragma unroll
  for (int i = 0; i < 8; ++i) { acc[i][0] = acc[i][1] = acc[i][2] = acc[i][3] = 0.f; }
#pragma unroll
  for (int j = 0; j < 8; ++j) {
    int li = j * 256 + t;
    at[li >> 6][li & 63] = attn[(size_t)(row0 + (li >> 6)) * DHEAD + (li & 63)];
  }
  for (int kc = 0; kc < 2; ++kc) {
#pragma unroll
    for (int j = 0; j < 32; ++j) {
      int li = j * 256 + t;
      wl[li >> 8][li & 255] = Wo[(size_t)(kc * 32 + (li >> 8)) * DMODEL + (li & 255)];
    }
    __syncthreads();
#pragma unroll
    for (int kk = 0; kk < 32; ++kk) {
      const float4 wv = *(const float4*)&wl[kk][cg * 4];
#pragma unroll
      for (int i = 0; i < 8; ++i) {
        const float a = at[rg * 8 + i][kc * 32 + kk];
        acc[i][0] = fmaf(a, wv.x, acc[i][0]);
        acc[i][1] = fmaf(a, wv.y, acc[i][1]);
        acc[i][2] = fmaf(a, wv.z, acc[i][2]);
        acc[i][3] = fmaf(a, wv.w, acc[i][3]);
      }
    }
    __syncthreads();
  }
  const float4 bb = *(const float4*)&bo[cg * 4];
#pragma unroll
  for (int i = 0; i < 8; ++i) {
    float4 r;
    r.x = acc[i][0] + bb.x; r.y = acc[i][1] + bb.y;
    r.z = acc[i][2] + bb.z; r.w = acc[i][3] + bb.w;
    *(float4*)&out[(size_t)(row0 + rg * 8 + i) * DMODEL + cg * 4] = r;
  }
}

// ---------------------------------------------------------------------------
extern "C" void kernel_launch(void* const* d_in, const int* in_sizes, int n_in,
                              void* d_out, int out_size, void* d_ws, size_t ws_size,
                              hipStream_t stream)
{
  (void)in_sizes; (void)n_in; (void)out_size; (void)ws_size;
  const float* x  = (const float*)d_in[0];
  const float* Wq = (const float*)d_in[1];
  const float* bq = (const float*)d_in[2];
  const float* Wo = (const float*)d_in[3];
  const float* bo = (const float*)d_in[4];
  float* out = (float*)d_out;
  char* ws = (char*)d_ws;
  f16* qh = (f16*)(ws);                              // 2 MB
  f16* kh = (f16*)(ws + (size_t)(2 << 20));          // 2 MB
  f16* vt = (f16*)(ws + (size_t)(4 << 20));          // 2 MB (transposed V)
  float* attn = (float*)(ws + (size_t)(6 << 20));    // 4 MB

  hipLaunchKernelGGL(qkv_proj,   dim3(512), dim3(256), 0, stream, x, Wq, bq, qh, kh, vt);
  hipLaunchKernelGGL(attn_fused, dim3(512), dim3(512), 0, stream, qh, kh, vt, attn);
  hipLaunchKernelGGL(out_proj,   dim3(512), dim3(256), 0, stream, attn, Wo, bo, out);
}

// Round 10
// 151.862 us; speedup vs baseline: 1.0035x; 1.0035x over previous
//
#include <hip/hip_runtime.h>
#include <hip/hip_fp16.h>
#include <stdint.h>

typedef _Float16 f16;
typedef _Float16 half8  __attribute__((ext_vector_type(8)));
typedef _Float16 half4v __attribute__((ext_vector_type(4)));
typedef float    f32x4  __attribute__((ext_vector_type(4)));

#define NBATCH 4
#define SEQ    4096
#define DMODEL 256
#define DHEAD  64
#define NQKV   192

// ---------------------------------------------------------------------------
// Kernel A: qkv = x @ W_qkv + b_qkv (fp32 VALU). Emits:
//   qh[row][d]   fp16, pre-scaled by 1/8 (exact pow2)
//   kh[row][d]   fp16 row-major        (QK^T stages this)
//   vt[b][d][seq] fp16 transposed      (PV stages this d-major)
// ---------------------------------------------------------------------------
__global__ __launch_bounds__(256) void qkv_proj(
    const float* __restrict__ x, const float* __restrict__ Wq,
    const float* __restrict__ bq,
    f16* __restrict__ qh, f16* __restrict__ kh, f16* __restrict__ vt)
{
  __shared__ float xs[32][64];      // 8 KB
  __shared__ float wsh[64][NQKV];   // 48 KB
  const int t = threadIdx.x;
  const int row0 = blockIdx.x * 32;
  const int cg = t & 31;            // 32 col-groups x 6 cols
  const int rg = t >> 5;            // 8 row-groups x 4 rows
  const int n0 = cg * 6;
  const int m0 = rg * 4;
  float acc[4][6];
#pragma unroll
  for (int i = 0; i < 4; ++i)
#pragma unroll
    for (int j = 0; j < 6; ++j) acc[i][j] = 0.f;

  for (int kc = 0; kc < 4; ++kc) {
    const int k0 = kc * 64;
#pragma unroll
    for (int j = 0; j < 8; ++j) {
      int li = j * 256 + t;
      xs[li >> 6][li & 63] = x[(size_t)(row0 + (li >> 6)) * DMODEL + k0 + (li & 63)];
    }
#pragma unroll
    for (int j = 0; j < 48; ++j) {
      int li = j * 256 + t;
      int r = li / NQKV, c = li % NQKV;
      wsh[r][c] = Wq[(size_t)(k0 + r) * NQKV + c];
    }
    __syncthreads();
#pragma unroll
    for (int kk4 = 0; kk4 < 16; ++kk4) {
      float4 a4[4];
#pragma unroll
      for (int i = 0; i < 4; ++i) a4[i] = *(const float4*)&xs[m0 + i][kk4 * 4];
#pragma unroll
      for (int e = 0; e < 4; ++e) {
        const int kk = kk4 * 4 + e;
        float2 b01 = *(const float2*)&wsh[kk][n0];
        float2 b23 = *(const float2*)&wsh[kk][n0 + 2];
        float2 b45 = *(const float2*)&wsh[kk][n0 + 4];
#pragma unroll
        for (int i = 0; i < 4; ++i) {
          const float a = (e == 0) ? a4[i].x : (e == 1) ? a4[i].y : (e == 2) ? a4[i].z : a4[i].w;
          acc[i][0] = fmaf(a, b01.x, acc[i][0]);
          acc[i][1] = fmaf(a, b01.y, acc[i][1]);
          acc[i][2] = fmaf(a, b23.x, acc[i][2]);
          acc[i][3] = fmaf(a, b23.y, acc[i][3]);
          acc[i][4] = fmaf(a, b45.x, acc[i][4]);
          acc[i][5] = fmaf(a, b45.y, acc[i][5]);
        }
      }
    }
    __syncthreads();
  }
  const int bi  = row0 >> 12;           // batch
  const int seq0 = (row0 & (SEQ - 1)) + m0;
#pragma unroll
  for (int j = 0; j < 6; ++j) {
    const int n = n0 + j;
    const float b = bq[n];
    const float v0 = acc[0][j] + b, v1 = acc[1][j] + b;
    const float v2 = acc[2][j] + b, v3 = acc[3][j] + b;
    if (n < 64) {
      const size_t r = (size_t)row0 + m0;
      qh[(r + 0) * DHEAD + n] = (f16)(v0 * 0.125f);
      qh[(r + 1) * DHEAD + n] = (f16)(v1 * 0.125f);
      qh[(r + 2) * DHEAD + n] = (f16)(v2 * 0.125f);
      qh[(r + 3) * DHEAD + n] = (f16)(v3 * 0.125f);
    } else if (n < 128) {
      const size_t r = (size_t)row0 + m0;
      kh[(r + 0) * DHEAD + (n - 64)] = (f16)v0;
      kh[(r + 1) * DHEAD + (n - 64)] = (f16)v1;
      kh[(r + 2) * DHEAD + (n - 64)] = (f16)v2;
      kh[(r + 3) * DHEAD + (n - 64)] = (f16)v3;
    } else {
      half4v pk = {(f16)v0, (f16)v1, (f16)v2, (f16)v3};
      *(half4v*)(vt + (size_t)bi * DHEAD * SEQ + (size_t)(n - 128) * SEQ + seq0) = pk;
    }
  }
}

// ---------------------------------------------------------------------------
// Kernel B: fused scores -> threshold -> masked softmax -> PV.
// R7 verified async template (global_load_lds, dbuf, counted vmcnt(4),
// SCHED_PIN before in-loop stage issue). 32 q-rows per block (two 16-row
// Q-tiles per wave against one staged K/V stream). R10 fix: launch_bounds
// cap removed — R9's (512,2) forced VGPR=128 and spilled ~80 regs to
// scratch (WRITE_SIZE 4->151 MB). Pa+Pb intrinsically need ~200 VGPRs.
// ---------------------------------------------------------------------------
#define WAVES  8
#define CHUNK  32
#define NCHUNK 16
#define BUFH   2048    // halves per buffer (4 KB = 32 rows x 64 halves)

__device__ __forceinline__ int khash(int row) {   // bijective per permuted tile
  return ((row >> 2) & 6) | ((row >> 1) & 1);
}

typedef __attribute__((address_space(3))) f16 as3_f16;
typedef __attribute__((address_space(1))) const f16 as1_f16;

__device__ __forceinline__ void gll16(const f16* g, f16* l) {
  __builtin_amdgcn_global_load_lds((as1_f16*)g, (as3_f16*)l, 16, 0, 0);
}

#define SCHED_PIN __builtin_amdgcn_sched_barrier(0)
#define WAITVM4 do { asm volatile("s_waitcnt vmcnt(4)" ::: "memory"); \
                     __builtin_amdgcn_sched_barrier(0); } while (0)
#define WAITVM0 do { asm volatile("s_waitcnt vmcnt(0)" ::: "memory"); \
                     __builtin_amdgcn_sched_barrier(0); } while (0)

// K chunk -> LDS[row 0..31][slot 0..7], source slot pre-XOR'd with khash(row)
__device__ __forceinline__ void stage_k(const f16* kchunk, f16* buf, int l) {
#pragma unroll
  for (int i = 0; i < 4; ++i) {
    const int row = i * 8 + (l >> 3);
    const int c8 = (l & 7) ^ khash(row);
    gll16(kchunk + row * DHEAD + c8 * 8, buf + i * 512);
  }
}

// V chunk -> LDS rows = d&31 (128 B), slots 0..3 = d<32, 4..7 = d>=32, XOR r&7
__device__ __forceinline__ void stage_v(const f16* vchunk, f16* buf, int l) {
#pragma unroll
  for (int i = 0; i < 4; ++i) {
    const int r = i * 8 + (l >> 3);
    const int jj = (l & 7) ^ (r & 7);
    const int d = ((jj >> 2) << 5) + r;
    const int kb = jj & 3;
    gll16(vchunk + (size_t)d * SEQ + kb * 8, buf + i * 512);
  }
}

__global__ __launch_bounds__(512) void attn_fused(
    const f16* __restrict__ qh, const f16* __restrict__ kh,
    const f16* __restrict__ vt, float* __restrict__ attn_out)
{
  __shared__ f16 stage[WAVES][2 * BUFH];     // 64 KB: per-wave double buffer
  __shared__ float selbuf[2][WAVES][32];
  __shared__ float zrow[32];

  const int tid = threadIdx.x;
  const int w = tid >> 6;
  const int l = tid & 63;
  const int qr = l & 15;
  const int g  = l >> 4;
  const int bi = blockIdx.x >> 7;
  const int rb = blockIdx.x & 127;
  const size_t qrow0  = (size_t)bi * SEQ + (size_t)rb * 32;   // 32 q-rows/block
  const size_t kvbase = (size_t)bi * SEQ * DHEAD;
  const int key0 = w * (CHUNK * NCHUNK);

  f16* const mybuf = &stage[w][0];

  // Q fragments for both tiles (B operand), q pre-scaled by 1/8 in qh.
  half8 qfa0, qfa1, qfb0, qfb1;
  {
    const f16* qpa = qh + (qrow0 + qr) * DHEAD;
    qfa0 = *(const half8*)(qpa + 8 * g);
    qfa1 = *(const half8*)(qpa + 32 + 8 * g);
    const f16* qpb = qh + (qrow0 + 16 + qr) * DHEAD;
    qfb0 = *(const half8*)(qpb + 8 * g);
    qfb1 = *(const half8*)(qpb + 32 + 8 * g);
  }

  half4v Pa[2 * NCHUNK], Pb[2 * NCHUNK];  // P[2kc+kt][r] = S[q][32kc+8g+4kt+r]
  float mna = 1e30f, mxa = -1e30f, mnb = 1e30f, mxb = -1e30f;

  // ---- QK^T: async pipeline, no barriers ----
  const f16* kc0 = kh + kvbase + (size_t)key0 * DHEAD;
  stage_k(kc0, mybuf, l);
  stage_k(kc0 + 32 * DHEAD, mybuf + BUFH, l);
#pragma unroll
  for (int kc = 0; kc < NCHUNK; ++kc) {
    if (kc < NCHUNK - 1) { WAITVM4; } else { WAITVM0; }
    const f16* bufp = mybuf + (kc & 1) * BUFH;
#pragma unroll
    for (int kt = 0; kt < 2; ++kt) {
      const int rowk = 8 * (qr >> 2) + 4 * kt + (qr & 3);   // permuted key row
      const int h = khash(rowk);
      half8 kf0 = *(const half8*)(bufp + rowk * DHEAD + ((g ^ h) * 8));
      half8 kf1 = *(const half8*)(bufp + rowk * DHEAD + (((4 + g) ^ h) * 8));
      f32x4 ca = {0.f, 0.f, 0.f, 0.f};
      ca = __builtin_amdgcn_mfma_f32_16x16x32_f16(kf0, qfa0, ca, 0, 0, 0);
      ca = __builtin_amdgcn_mfma_f32_16x16x32_f16(kf1, qfa1, ca, 0, 0, 0);
      f32x4 cb = {0.f, 0.f, 0.f, 0.f};
      cb = __builtin_amdgcn_mfma_f32_16x16x32_f16(kf0, qfb0, cb, 0, 0, 0);
      cb = __builtin_amdgcn_mfma_f32_16x16x32_f16(kf1, qfb1, cb, 0, 0, 0);
      mna = fminf(mna, fminf(fminf(ca[0], ca[1]), fminf(ca[2], ca[3])));
      mxa = fmaxf(mxa, fmaxf(fmaxf(ca[0], ca[1]), fmaxf(ca[2], ca[3])));
      mnb = fminf(mnb, fminf(fminf(cb[0], cb[1]), fminf(cb[2], cb[3])));
      mxb = fmaxf(mxb, fmaxf(fmaxf(cb[0], cb[1]), fmaxf(cb[2], cb[3])));
      Pa[kc * 2 + kt] = (half4v){(f16)ca[0], (f16)ca[1], (f16)ca[2], (f16)ca[3]};
      Pb[kc * 2 + kt] = (half4v){(f16)cb[0], (f16)cb[1], (f16)cb[2], (f16)cb[3]};
    }
    if (kc + 2 < NCHUNK) {
      SCHED_PIN;   // all reads of buf[kc&1] complete (in-order DS) before DMA
      stage_k(kc0 + (size_t)(kc + 2) * 32 * DHEAD, mybuf + (kc & 1) * BUFH, l);
    }
  }

  // ---- per-row min/max across lanes and waves (both tiles) ----
  mna = fminf(mna, __shfl_xor(mna, 16, 64));
  mna = fminf(mna, __shfl_xor(mna, 32, 64));
  mxa = fmaxf(mxa, __shfl_xor(mxa, 16, 64));
  mxa = fmaxf(mxa, __shfl_xor(mxa, 32, 64));
  mnb = fminf(mnb, __shfl_xor(mnb, 16, 64));
  mnb = fminf(mnb, __shfl_xor(mnb, 32, 64));
  mxb = fmaxf(mxb, __shfl_xor(mxb, 16, 64));
  mxb = fmaxf(mxb, __shfl_xor(mxb, 32, 64));
  if (l < 16) {
    selbuf[0][w][qr] = mna;      selbuf[1][w][qr] = mxa;
    selbuf[0][w][16 + qr] = mnb; selbuf[1][w][16 + qr] = mxb;
  }
  __syncthreads();
  float loa = 1e30f, hia = -1e30f, lob = 1e30f, hib = -1e30f;
#pragma unroll
  for (int j = 0; j < WAVES; ++j) {
    loa = fminf(loa, selbuf[0][j][qr]);      hia = fmaxf(hia, selbuf[1][j][qr]);
    lob = fminf(lob, selbuf[0][j][16 + qr]); hib = fmaxf(hib, selbuf[1][j][16 + qr]);
  }
  __syncthreads();   // lo/hi reads done before iter 0 overwrites selbuf[0]

  // ---- bisection on sampled count (512 of 4096 per row; target 256) ----
#pragma unroll
  for (int it = 0; it < 8; ++it) {
    const float tma = 0.5f * (loa + hia);
    const float tmb = 0.5f * (lob + hib);
    const f16 tha = (f16)tma, thb = (f16)tmb;
    int ca = 0, cb = 0;
#pragma unroll
    for (int j = 0; j < 2 * NCHUNK; j += 8) {
      half4v sa = Pa[j], sb = Pb[j];
      ca += (sa[0] >= tha) + (sa[1] >= tha) + (sa[2] >= tha) + (sa[3] >= tha);
      cb += (sb[0] >= thb) + (sb[1] >= thb) + (sb[2] >= thb) + (sb[3] >= thb);
    }
    ca += __shfl_xor(ca, 16, 64); ca += __shfl_xor(ca, 32, 64);
    cb += __shfl_xor(cb, 16, 64); cb += __shfl_xor(cb, 32, 64);
    if (l < 16) {
      selbuf[it & 1][w][qr] = (float)ca;
      selbuf[it & 1][w][16 + qr] = (float)cb;
    }
    __syncthreads();
    float ta = 0.f, tb = 0.f;
#pragma unroll
    for (int j = 0; j < WAVES; ++j) {
      ta += selbuf[it & 1][j][qr];
      tb += selbuf[it & 1][j][16 + qr];
    }
    if (ta >= 256.f) loa = tma; else hia = tma;
    if (tb >= 256.f) lob = tmb; else hib = tmb;
  }
  const float thra = loa, thrb = lob;

  // ---- prefetch V chunks 0/1 (exp loop + z-barrier hide the latency) ----
  const f16* vchunk0 = vt + (size_t)bi * DHEAD * SEQ + key0;
  stage_v(vchunk0, mybuf, l);
  stage_v(vchunk0 + 32, mybuf + BUFH, l);

  // ---- exp in place (masked -> exp(0)=1, matches softmax(scores*mask)) ----
  float za = 0.f, zb = 0.f;
#pragma unroll
  for (int j = 0; j < 2 * NCHUNK; ++j) {
    half4v sa = Pa[j];
    float a0 = (float)sa[0], a1 = (float)sa[1], a2 = (float)sa[2], a3 = (float)sa[3];
    a0 = (a0 >= thra) ? __expf(a0) : 1.f;
    a1 = (a1 >= thra) ? __expf(a1) : 1.f;
    a2 = (a2 >= thra) ? __expf(a2) : 1.f;
    a3 = (a3 >= thra) ? __expf(a3) : 1.f;
    za += (a0 + a1) + (a2 + a3);
    Pa[j] = (half4v){(f16)a0, (f16)a1, (f16)a2, (f16)a3};
    half4v sb = Pb[j];
    float b0 = (float)sb[0], b1 = (float)sb[1], b2 = (float)sb[2], b3 = (float)sb[3];
    b0 = (b0 >= thrb) ? __expf(b0) : 1.f;
    b1 = (b1 >= thrb) ? __expf(b1) : 1.f;
    b2 = (b2 >= thrb) ? __expf(b2) : 1.f;
    b3 = (b3 >= thrb) ? __expf(b3) : 1.f;
    zb += (b0 + b1) + (b2 + b3);
    Pb[j] = (half4v){(f16)b0, (f16)b1, (f16)b2, (f16)b3};
  }
  za += __shfl_xor(za, 16, 64); za += __shfl_xor(za, 32, 64);
  zb += __shfl_xor(zb, 16, 64); zb += __shfl_xor(zb, 32, 64);
  if (l < 16) { selbuf[0][w][qr] = za; selbuf[0][w][16 + qr] = zb; }
  __syncthreads();
  if (w == 0 && l < 32) {
    float t2 = 0.f;
#pragma unroll
    for (int j = 0; j < WAVES; ++j) t2 += selbuf[0][j][l];
    zrow[l] = t2;   // consumed after the post-PV barrier
  }

  // ---- PV: O^T = V^T P^T; A = V^T (b128 LDS reads), B = P register concat ----
  f32x4 acca[4], accb[4];
#pragma unroll
  for (int p = 0; p < 4; ++p) {
    acca[p] = (f32x4){0.f, 0.f, 0.f, 0.f};
    accb[p] = (f32x4){0.f, 0.f, 0.f, 0.f};
  }

#pragma unroll
  for (int kc = 0; kc < NCHUNK; ++kc) {
    if (kc < NCHUNK - 1) { WAITVM4; } else { WAITVM0; }
    const f16* bufp = mybuf + (kc & 1) * BUFH;
    const half8 pba = __builtin_shufflevector(Pa[kc * 2], Pa[kc * 2 + 1],
                                              0, 1, 2, 3, 4, 5, 6, 7);
    const half8 pbb = __builtin_shufflevector(Pb[kc * 2], Pb[kc * 2 + 1],
                                              0, 1, 2, 3, 4, 5, 6, 7);
#pragma unroll
    for (int pnl = 0; pnl < 4; ++pnl) {
      const int d = 16 * pnl + qr;
      const int r = d & 31;
      const int j = (((d >> 5) << 2) + g) ^ (r & 7);
      half8 va = *(const half8*)(bufp + r * 64 + j * 8);
      acca[pnl] = __builtin_amdgcn_mfma_f32_16x16x32_f16(va, pba, acca[pnl], 0, 0, 0);
      accb[pnl] = __builtin_amdgcn_mfma_f32_16x16x32_f16(va, pbb, accb[pnl], 0, 0, 0);
    }
    if (kc + 2 < NCHUNK) {
      SCHED_PIN;   // all reads of buf[kc&1] complete (in-order DS) before DMA
      stage_v(vchunk0 + (kc + 2) * 32, mybuf + (kc & 1) * BUFH, l);
    }
  }

  // ---- cross-wave reduce + divide by Z: TWO 16-row passes so the 68-pad
  // red (16x68x4 = 4352 B) fits the 8 KB wave region ----
  float* red = (float*)mybuf;
#pragma unroll
  for (int pnl = 0; pnl < 4; ++pnl)
    *(f32x4*)&red[qr * 68 + pnl * 16 + 4 * g] = acca[pnl];
  __syncthreads();
#pragma unroll
  for (int oo = 0; oo < 2; ++oo) {
    const int o = tid * 2 + oo;
    const int i = o >> 6, n = o & 63;
    float s = 0.f;
#pragma unroll
    for (int j = 0; j < WAVES; ++j) s += ((const float*)&stage[j][0])[i * 68 + n];
    attn_out[(qrow0 + i) * DHEAD + n] = s / zrow[i];
  }
  __syncthreads();   // pass-a reads complete before pass-b overwrites red
#pragma unroll
  for (int pnl = 0; pnl < 4; ++pnl)
    *(f32x4*)&red[qr * 68 + pnl * 16 + 4 * g] = accb[pnl];
  __syncthreads();
#pragma unroll
  for (int oo = 0; oo < 2; ++oo) {
    const int o = tid * 2 + oo;
    const int i = o >> 6, n = o & 63;
    float s = 0.f;
#pragma unroll
    for (int j = 0; j < WAVES; ++j) s += ((const float*)&stage[j][0])[i * 68 + n];
    attn_out[(qrow0 + 16 + i) * DHEAD + n] = s / zrow[16 + i];
  }
}

// ---------------------------------------------------------------------------
// Kernel C: out = attn_out @ W_out + b_out (fp32). 32 rows x 256 cols per WG.
// ---------------------------------------------------------------------------
__global__ __launch_bounds__(256) void out_proj(
    const float* __restrict__ attn, const float* __restrict__ Wo,
    const float* __restrict__ bo, float* __restrict__ out)
{
  __shared__ float wl[32][DMODEL];  // 32 KB
  __shared__ float at[32][DHEAD];   // 8 KB
  const int t = threadIdx.x;
  const int row0 = blockIdx.x * 32;
  const int rg = t >> 6;
  const int cg = t & 63;
  float acc[8][4];
#pragma unroll
  for (int i = 0; i < 8; ++i) { acc[i][0] = acc[i][1] = acc[i][2] = acc[i][3] = 0.f; }
#pragma unroll
  for (int j = 0; j < 8; ++j) {
    int li = j * 256 + t;
    at[li >> 6][li & 63] = attn[(size_t)(row0 + (li >> 6)) * DHEAD + (li & 63)];
  }
  for (int kc = 0; kc < 2; ++kc) {
#pragma unroll
    for (int j = 0; j < 32; ++j) {
      int li = j * 256 + t;
      wl[li >> 8][li & 255] = Wo[(size_t)(kc * 32 + (li >> 8)) * DMODEL + (li & 255)];
    }
    __syncthreads();
#pragma unroll
    for (int kk = 0; kk < 32; ++kk) {
      const float4 wv = *(const float4*)&wl[kk][cg * 4];
#pragma unroll
      for (int i = 0; i < 8; ++i) {
        const float a = at[rg * 8 + i][kc * 32 + kk];
        acc[i][0] = fmaf(a, wv.x, acc[i][0]);
        acc[i][1] = fmaf(a, wv.y, acc[i][1]);
        acc[i][2] = fmaf(a, wv.z, acc[i][2]);
        acc[i][3] = fmaf(a, wv.w, acc[i][3]);
      }
    }
    __syncthreads();
  }
  const float4 bb = *(const float4*)&bo[cg * 4];
#pragma unroll
  for (int i = 0; i < 8; ++i) {
    float4 r;
    r.x = acc[i][0] + bb.x; r.y = acc[i][1] + bb.y;
    r.z = acc[i][2] + bb.z; r.w = acc[i][3] + bb.w;
    *(float4*)&out[(size_t)(row0 + rg * 8 + i) * DMODEL + cg * 4] = r;
  }
}

// ---------------------------------------------------------------------------
extern "C" void kernel_launch(void* const* d_in, const int* in_sizes, int n_in,
                              void* d_out, int out_size, void* d_ws, size_t ws_size,
                              hipStream_t stream)
{
  (void)in_sizes; (void)n_in; (void)out_size; (void)ws_size;
  const float* x  = (const float*)d_in[0];
  const float* Wq = (const float*)d_in[1];
  const float* bq = (const float*)d_in[2];
  const float* Wo = (const float*)d_in[3];
  const float* bo = (const float*)d_in[4];
  float* out = (float*)d_out;
  char* ws = (char*)d_ws;
  f16* qh = (f16*)(ws);                              // 2 MB
  f16* kh = (f16*)(ws + (size_t)(2 << 20));          // 2 MB
  f16* vt = (f16*)(ws + (size_t)(4 << 20));          // 2 MB (transposed V)
  float* attn = (float*)(ws + (size_t)(6 << 20));    // 4 MB

  hipLaunchKernelGGL(qkv_proj,   dim3(512), dim3(256), 0, stream, x, Wq, bq, qh, kh, vt);
  hipLaunchKernelGGL(attn_fused, dim3(512), dim3(512), 0, stream, qh, kh, vt, attn);
  hipLaunchKernelGGL(out_proj,   dim3(512), dim3(256), 0, stream, attn, Wo, bo, out);
}

// Round 11
// 151.810 us; speedup vs baseline: 1.0038x; 1.0003x over previous
//
#include <hip/hip_runtime.h>
#include <hip/hip_fp16.h>
#include <stdint.h>

typedef _Float16 f16;
typedef _Float16 half8  __attribute__((ext_vector_type(8)));
typedef _Float16 half4v __attribute__((ext_vector_type(4)));
typedef float    f32x4  __attribute__((ext_vector_type(4)));

#define NBATCH 4
#define SEQ    4096
#define DMODEL 256
#define DHEAD  64
#define NQKV   192

// ---------------------------------------------------------------------------
// Kernel A: qkv = x @ W_qkv + b_qkv (fp32 VALU). Emits:
//   qh[row][d]   fp16, pre-scaled by 1/8 (exact pow2)
//   kh[row][d]   fp16 row-major        (QK^T stages this)
//   vt[b][d][seq] fp16 transposed      (PV stages this d-major)
// ---------------------------------------------------------------------------
__global__ __launch_bounds__(256) void qkv_proj(
    const float* __restrict__ x, const float* __restrict__ Wq,
    const float* __restrict__ bq,
    f16* __restrict__ qh, f16* __restrict__ kh, f16* __restrict__ vt)
{
  __shared__ float xs[32][64];      // 8 KB
  __shared__ float wsh[64][NQKV];   // 48 KB
  const int t = threadIdx.x;
  const int row0 = blockIdx.x * 32;
  const int cg = t & 31;            // 32 col-groups x 6 cols
  const int rg = t >> 5;            // 8 row-groups x 4 rows
  const int n0 = cg * 6;
  const int m0 = rg * 4;
  float acc[4][6];
#pragma unroll
  for (int i = 0; i < 4; ++i)
#pragma unroll
    for (int j = 0; j < 6; ++j) acc[i][j] = 0.f;

  for (int kc = 0; kc < 4; ++kc) {
    const int k0 = kc * 64;
#pragma unroll
    for (int j = 0; j < 8; ++j) {
      int li = j * 256 + t;
      xs[li >> 6][li & 63] = x[(size_t)(row0 + (li >> 6)) * DMODEL + k0 + (li & 63)];
    }
#pragma unroll
    for (int j = 0; j < 48; ++j) {
      int li = j * 256 + t;
      int r = li / NQKV, c = li % NQKV;
      wsh[r][c] = Wq[(size_t)(k0 + r) * NQKV + c];
    }
    __syncthreads();
#pragma unroll
    for (int kk4 = 0; kk4 < 16; ++kk4) {
      float4 a4[4];
#pragma unroll
      for (int i = 0; i < 4; ++i) a4[i] = *(const float4*)&xs[m0 + i][kk4 * 4];
#pragma unroll
      for (int e = 0; e < 4; ++e) {
        const int kk = kk4 * 4 + e;
        float2 b01 = *(const float2*)&wsh[kk][n0];
        float2 b23 = *(const float2*)&wsh[kk][n0 + 2];
        float2 b45 = *(const float2*)&wsh[kk][n0 + 4];
#pragma unroll
        for (int i = 0; i < 4; ++i) {
          const float a = (e == 0) ? a4[i].x : (e == 1) ? a4[i].y : (e == 2) ? a4[i].z : a4[i].w;
          acc[i][0] = fmaf(a, b01.x, acc[i][0]);
          acc[i][1] = fmaf(a, b01.y, acc[i][1]);
          acc[i][2] = fmaf(a, b23.x, acc[i][2]);
          acc[i][3] = fmaf(a, b23.y, acc[i][3]);
          acc[i][4] = fmaf(a, b45.x, acc[i][4]);
          acc[i][5] = fmaf(a, b45.y, acc[i][5]);
        }
      }
    }
    __syncthreads();
  }
  const int bi  = row0 >> 12;           // batch
  const int seq0 = (row0 & (SEQ - 1)) + m0;
#pragma unroll
  for (int j = 0; j < 6; ++j) {
    const int n = n0 + j;
    const float b = bq[n];
    const float v0 = acc[0][j] + b, v1 = acc[1][j] + b;
    const float v2 = acc[2][j] + b, v3 = acc[3][j] + b;
    if (n < 64) {
      const size_t r = (size_t)row0 + m0;
      qh[(r + 0) * DHEAD + n] = (f16)(v0 * 0.125f);
      qh[(r + 1) * DHEAD + n] = (f16)(v1 * 0.125f);
      qh[(r + 2) * DHEAD + n] = (f16)(v2 * 0.125f);
      qh[(r + 3) * DHEAD + n] = (f16)(v3 * 0.125f);
    } else if (n < 128) {
      const size_t r = (size_t)row0 + m0;
      kh[(r + 0) * DHEAD + (n - 64)] = (f16)v0;
      kh[(r + 1) * DHEAD + (n - 64)] = (f16)v1;
      kh[(r + 2) * DHEAD + (n - 64)] = (f16)v2;
      kh[(r + 3) * DHEAD + (n - 64)] = (f16)v3;
    } else {
      half4v pk = {(f16)v0, (f16)v1, (f16)v2, (f16)v3};
      *(half4v*)(vt + (size_t)bi * DHEAD * SEQ + (size_t)(n - 128) * SEQ + seq0) = pk;
    }
  }
}

// ---------------------------------------------------------------------------
// Kernel B: fused scores -> threshold -> masked softmax -> PV.
// R7 verified async template (global_load_lds, dbuf, counted vmcnt(4),
// SCHED_PIN before in-loop stage issue). 32 q-rows per block (two 16-row
// Q-tiles per wave). R11 fix: __launch_bounds__(512, 1) — without an explicit
// min-waves-per-EU, LLVM derives 4 waves/SIMD from the LDS-allowed occupancy
// and caps VGPR at 128, spilling ~80 regs (R9/R10: WRITE_SIZE 4->151 MB).
// Min=1 lifts the cap to 512; the kernel needs ~200.
// ---------------------------------------------------------------------------
#define WAVES  8
#define CHUNK  32
#define NCHUNK 16
#define BUFH   2048    // halves per buffer (4 KB = 32 rows x 64 halves)

__device__ __forceinline__ int khash(int row) {   // bijective per permuted tile
  return ((row >> 2) & 6) | ((row >> 1) & 1);
}

typedef __attribute__((address_space(3))) f16 as3_f16;
typedef __attribute__((address_space(1))) const f16 as1_f16;

__device__ __forceinline__ void gll16(const f16* g, f16* l) {
  __builtin_amdgcn_global_load_lds((as1_f16*)g, (as3_f16*)l, 16, 0, 0);
}

#define SCHED_PIN __builtin_amdgcn_sched_barrier(0)
#define WAITVM4 do { asm volatile("s_waitcnt vmcnt(4)" ::: "memory"); \
                     __builtin_amdgcn_sched_barrier(0); } while (0)
#define WAITVM0 do { asm volatile("s_waitcnt vmcnt(0)" ::: "memory"); \
                     __builtin_amdgcn_sched_barrier(0); } while (0)

// K chunk -> LDS[row 0..31][slot 0..7], source slot pre-XOR'd with khash(row)
__device__ __forceinline__ void stage_k(const f16* kchunk, f16* buf, int l) {
#pragma unroll
  for (int i = 0; i < 4; ++i) {
    const int row = i * 8 + (l >> 3);
    const int c8 = (l & 7) ^ khash(row);
    gll16(kchunk + row * DHEAD + c8 * 8, buf + i * 512);
  }
}

// V chunk -> LDS rows = d&31 (128 B), slots 0..3 = d<32, 4..7 = d>=32, XOR r&7
__device__ __forceinline__ void stage_v(const f16* vchunk, f16* buf, int l) {
#pragma unroll
  for (int i = 0; i < 4; ++i) {
    const int r = i * 8 + (l >> 3);
    const int jj = (l & 7) ^ (r & 7);
    const int d = ((jj >> 2) << 5) + r;
    const int kb = jj & 3;
    gll16(vchunk + (size_t)d * SEQ + kb * 8, buf + i * 512);
  }
}

__global__ __launch_bounds__(512, 1) void attn_fused(
    const f16* __restrict__ qh, const f16* __restrict__ kh,
    const f16* __restrict__ vt, float* __restrict__ attn_out)
{
  __shared__ f16 stage[WAVES][2 * BUFH];     // 64 KB: per-wave double buffer
  __shared__ float selbuf[2][WAVES][32];
  __shared__ float zrow[32];

  const int tid = threadIdx.x;
  const int w = tid >> 6;
  const int l = tid & 63;
  const int qr = l & 15;
  const int g  = l >> 4;
  const int bi = blockIdx.x >> 7;
  const int rb = blockIdx.x & 127;
  const size_t qrow0  = (size_t)bi * SEQ + (size_t)rb * 32;   // 32 q-rows/block
  const size_t kvbase = (size_t)bi * SEQ * DHEAD;
  const int key0 = w * (CHUNK * NCHUNK);

  f16* const mybuf = &stage[w][0];

  // Q fragments for both tiles (B operand), q pre-scaled by 1/8 in qh.
  half8 qfa0, qfa1, qfb0, qfb1;
  {
    const f16* qpa = qh + (qrow0 + qr) * DHEAD;
    qfa0 = *(const half8*)(qpa + 8 * g);
    qfa1 = *(const half8*)(qpa + 32 + 8 * g);
    const f16* qpb = qh + (qrow0 + 16 + qr) * DHEAD;
    qfb0 = *(const half8*)(qpb + 8 * g);
    qfb1 = *(const half8*)(qpb + 32 + 8 * g);
  }

  half4v Pa[2 * NCHUNK], Pb[2 * NCHUNK];  // P[2kc+kt][r] = S[q][32kc+8g+4kt+r]
  float mna = 1e30f, mxa = -1e30f, mnb = 1e30f, mxb = -1e30f;

  // ---- QK^T: async pipeline, no barriers ----
  const f16* kc0 = kh + kvbase + (size_t)key0 * DHEAD;
  stage_k(kc0, mybuf, l);
  stage_k(kc0 + 32 * DHEAD, mybuf + BUFH, l);
#pragma unroll
  for (int kc = 0; kc < NCHUNK; ++kc) {
    if (kc < NCHUNK - 1) { WAITVM4; } else { WAITVM0; }
    const f16* bufp = mybuf + (kc & 1) * BUFH;
#pragma unroll
    for (int kt = 0; kt < 2; ++kt) {
      const int rowk = 8 * (qr >> 2) + 4 * kt + (qr & 3);   // permuted key row
      const int h = khash(rowk);
      half8 kf0 = *(const half8*)(bufp + rowk * DHEAD + ((g ^ h) * 8));
      half8 kf1 = *(const half8*)(bufp + rowk * DHEAD + (((4 + g) ^ h) * 8));
      f32x4 ca = {0.f, 0.f, 0.f, 0.f};
      ca = __builtin_amdgcn_mfma_f32_16x16x32_f16(kf0, qfa0, ca, 0, 0, 0);
      ca = __builtin_amdgcn_mfma_f32_16x16x32_f16(kf1, qfa1, ca, 0, 0, 0);
      f32x4 cb = {0.f, 0.f, 0.f, 0.f};
      cb = __builtin_amdgcn_mfma_f32_16x16x32_f16(kf0, qfb0, cb, 0, 0, 0);
      cb = __builtin_amdgcn_mfma_f32_16x16x32_f16(kf1, qfb1, cb, 0, 0, 0);
      mna = fminf(mna, fminf(fminf(ca[0], ca[1]), fminf(ca[2], ca[3])));
      mxa = fmaxf(mxa, fmaxf(fmaxf(ca[0], ca[1]), fmaxf(ca[2], ca[3])));
      mnb = fminf(mnb, fminf(fminf(cb[0], cb[1]), fminf(cb[2], cb[3])));
      mxb = fmaxf(mxb, fmaxf(fmaxf(cb[0], cb[1]), fmaxf(cb[2], cb[3])));
      Pa[kc * 2 + kt] = (half4v){(f16)ca[0], (f16)ca[1], (f16)ca[2], (f16)ca[3]};
      Pb[kc * 2 + kt] = (half4v){(f16)cb[0], (f16)cb[1], (f16)cb[2], (f16)cb[3]};
    }
    if (kc + 2 < NCHUNK) {
      SCHED_PIN;   // all reads of buf[kc&1] complete (in-order DS) before DMA
      stage_k(kc0 + (size_t)(kc + 2) * 32 * DHEAD, mybuf + (kc & 1) * BUFH, l);
    }
  }

  // ---- per-row min/max across lanes and waves (both tiles) ----
  mna = fminf(mna, __shfl_xor(mna, 16, 64));
  mna = fminf(mna, __shfl_xor(mna, 32, 64));
  mxa = fmaxf(mxa, __shfl_xor(mxa, 16, 64));
  mxa = fmaxf(mxa, __shfl_xor(mxa, 32, 64));
  mnb = fminf(mnb, __shfl_xor(mnb, 16, 64));
  mnb = fminf(mnb, __shfl_xor(mnb, 32, 64));
  mxb = fmaxf(mxb, __shfl_xor(mxb, 16, 64));
  mxb = fmaxf(mxb, __shfl_xor(mxb, 32, 64));
  if (l < 16) {
    selbuf[0][w][qr] = mna;      selbuf[1][w][qr] = mxa;
    selbuf[0][w][16 + qr] = mnb; selbuf[1][w][16 + qr] = mxb;
  }
  __syncthreads();
  float loa = 1e30f, hia = -1e30f, lob = 1e30f, hib = -1e30f;
#pragma unroll
  for (int j = 0; j < WAVES; ++j) {
    loa = fminf(loa, selbuf[0][j][qr]);      hia = fmaxf(hia, selbuf[1][j][qr]);
    lob = fminf(lob, selbuf[0][j][16 + qr]); hib = fmaxf(hib, selbuf[1][j][16 + qr]);
  }
  __syncthreads();   // lo/hi reads done before iter 0 overwrites selbuf[0]

  // ---- bisection on sampled count (512 of 4096 per row; target 256) ----
#pragma unroll
  for (int it = 0; it < 8; ++it) {
    const float tma = 0.5f * (loa + hia);
    const float tmb = 0.5f * (lob + hib);
    const f16 tha = (f16)tma, thb = (f16)tmb;
    int ca = 0, cb = 0;
#pragma unroll
    for (int j = 0; j < 2 * NCHUNK; j += 8) {
      half4v sa = Pa[j], sb = Pb[j];
      ca += (sa[0] >= tha) + (sa[1] >= tha) + (sa[2] >= tha) + (sa[3] >= tha);
      cb += (sb[0] >= thb) + (sb[1] >= thb) + (sb[2] >= thb) + (sb[3] >= thb);
    }
    ca += __shfl_xor(ca, 16, 64); ca += __shfl_xor(ca, 32, 64);
    cb += __shfl_xor(cb, 16, 64); cb += __shfl_xor(cb, 32, 64);
    if (l < 16) {
      selbuf[it & 1][w][qr] = (float)ca;
      selbuf[it & 1][w][16 + qr] = (float)cb;
    }
    __syncthreads();
    float ta = 0.f, tb = 0.f;
#pragma unroll
    for (int j = 0; j < WAVES; ++j) {
      ta += selbuf[it & 1][j][qr];
      tb += selbuf[it & 1][j][16 + qr];
    }
    if (ta >= 256.f) loa = tma; else hia = tma;
    if (tb >= 256.f) lob = tmb; else hib = tmb;
  }
  const float thra = loa, thrb = lob;

  // ---- prefetch V chunks 0/1 (exp loop + z-barrier hide the latency) ----
  const f16* vchunk0 = vt + (size_t)bi * DHEAD * SEQ + key0;
  stage_v(vchunk0, mybuf, l);
  stage_v(vchunk0 + 32, mybuf + BUFH, l);

  // ---- exp in place (masked -> exp(0)=1, matches softmax(scores*mask)) ----
  float za = 0.f, zb = 0.f;
#pragma unroll
  for (int j = 0; j < 2 * NCHUNK; ++j) {
    half4v sa = Pa[j];
    float a0 = (float)sa[0], a1 = (float)sa[1], a2 = (float)sa[2], a3 = (float)sa[3];
    a0 = (a0 >= thra) ? __expf(a0) : 1.f;
    a1 = (a1 >= thra) ? __expf(a1) : 1.f;
    a2 = (a2 >= thra) ? __expf(a2) : 1.f;
    a3 = (a3 >= thra) ? __expf(a3) : 1.f;
    za += (a0 + a1) + (a2 + a3);
    Pa[j] = (half4v){(f16)a0, (f16)a1, (f16)a2, (f16)a3};
    half4v sb = Pb[j];
    float b0 = (float)sb[0], b1 = (float)sb[1], b2 = (float)sb[2], b3 = (float)sb[3];
    b0 = (b0 >= thrb) ? __expf(b0) : 1.f;
    b1 = (b1 >= thrb) ? __expf(b1) : 1.f;
    b2 = (b2 >= thrb) ? __expf(b2) : 1.f;
    b3 = (b3 >= thrb) ? __expf(b3) : 1.f;
    zb += (b0 + b1) + (b2 + b3);
    Pb[j] = (half4v){(f16)b0, (f16)b1, (f16)b2, (f16)b3};
  }
  za += __shfl_xor(za, 16, 64); za += __shfl_xor(za, 32, 64);
  zb += __shfl_xor(zb, 16, 64); zb += __shfl_xor(zb, 32, 64);
  if (l < 16) { selbuf[0][w][qr] = za; selbuf[0][w][16 + qr] = zb; }
  __syncthreads();
  if (w == 0 && l < 32) {
    float t2 = 0.f;
#pragma unroll
    for (int j = 0; j < WAVES; ++j) t2 += selbuf[0][j][l];
    zrow[l] = t2;   // consumed after the post-PV barrier
  }

  // ---- PV: O^T = V^T P^T; A = V^T (b128 LDS reads), B = P register concat ----
  f32x4 acca[4], accb[4];
#pragma unroll
  for (int p = 0; p < 4; ++p) {
    acca[p] = (f32x4){0.f, 0.f, 0.f, 0.f};
    accb[p] = (f32x4){0.f, 0.f, 0.f, 0.f};
  }

#pragma unroll
  for (int kc = 0; kc < NCHUNK; ++kc) {
    if (kc < NCHUNK - 1) { WAITVM4; } else { WAITVM0; }
    const f16* bufp = mybuf + (kc & 1) * BUFH;
    const half8 pba = __builtin_shufflevector(Pa[kc * 2], Pa[kc * 2 + 1],
                                              0, 1, 2, 3, 4, 5, 6, 7);
    const half8 pbb = __builtin_shufflevector(Pb[kc * 2], Pb[kc * 2 + 1],
                                              0, 1, 2, 3, 4, 5, 6, 7);
#pragma unroll
    for (int pnl = 0; pnl < 4; ++pnl) {
      const int d = 16 * pnl + qr;
      const int r = d & 31;
      const int j = (((d >> 5) << 2) + g) ^ (r & 7);
      half8 va = *(const half8*)(bufp + r * 64 + j * 8);
      acca[pnl] = __builtin_amdgcn_mfma_f32_16x16x32_f16(va, pba, acca[pnl], 0, 0, 0);
      accb[pnl] = __builtin_amdgcn_mfma_f32_16x16x32_f16(va, pbb, accb[pnl], 0, 0, 0);
    }
    if (kc + 2 < NCHUNK) {
      SCHED_PIN;   // all reads of buf[kc&1] complete (in-order DS) before DMA
      stage_v(vchunk0 + (kc + 2) * 32, mybuf + (kc & 1) * BUFH, l);
    }
  }

  // ---- cross-wave reduce + divide by Z: TWO 16-row passes so the 68-pad
  // red (16x68x4 = 4352 B) fits the 8 KB wave region ----
  float* red = (float*)mybuf;
#pragma unroll
  for (int pnl = 0; pnl < 4; ++pnl)
    *(f32x4*)&red[qr * 68 + pnl * 16 + 4 * g] = acca[pnl];
  __syncthreads();
#pragma unroll
  for (int oo = 0; oo < 2; ++oo) {
    const int o = tid * 2 + oo;
    const int i = o >> 6, n = o & 63;
    float s = 0.f;
#pragma unroll
    for (int j = 0; j < WAVES; ++j) s += ((const float*)&stage[j][0])[i * 68 + n];
    attn_out[(qrow0 + i) * DHEAD + n] = s / zrow[i];
  }
  __syncthreads();   // pass-a reads complete before pass-b overwrites red
#pragma unroll
  for (int pnl = 0; pnl < 4; ++pnl)
    *(f32x4*)&red[qr * 68 + pnl * 16 + 4 * g] = accb[pnl];
  __syncthreads();
#pragma unroll
  for (int oo = 0; oo < 2; ++oo) {
    const int o = tid * 2 + oo;
    const int i = o >> 6, n = o & 63;
    float s = 0.f;
#pragma unroll
    for (int j = 0; j < WAVES; ++j) s += ((const float*)&stage[j][0])[i * 68 + n];
    attn_out[(qrow0 + 16 + i) * DHEAD + n] = s / zrow[16 + i];
  }
}

// ---------------------------------------------------------------------------
// Kernel C: out = attn_out @ W_out + b_out (fp32). 32 rows x 256 cols per WG.
// ---------------------------------------------------------------------------
__global__ __launch_bounds__(256) void out_proj(
    const float* __restrict__ attn, const float* __restrict__ Wo,
    const float* __restrict__ bo, float* __restrict__ out)
{
  __shared__ float wl[32][DMODEL];  // 32 KB
  __shared__ float at[32][DHEAD];   // 8 KB
  const int t = threadIdx.x;
  const int row0 = blockIdx.x * 32;
  const int rg = t >> 6;
  const int cg = t & 63;
  float acc[8][4];
#pragma unroll
  for (int i = 0; i < 8; ++i) { acc[i][0] = acc[i][1] = acc[i][2] = acc[i][3] = 0.f; }
#pragma unroll
  for (int j = 0; j < 8; ++j) {
    int li = j * 256 + t;
    at[li >> 6][li & 63] = attn[(size_t)(row0 + (li >> 6)) * DHEAD + (li & 63)];
  }
  for (int kc = 0; kc < 2; ++kc) {
#pragma unroll
    for (int j = 0; j < 32; ++j) {
      int li = j * 256 + t;
      wl[li >> 8][li & 255] = Wo[(size_t)(kc * 32 + (li >> 8)) * DMODEL + (li & 255)];
    }
    __syncthreads();
#pragma unroll
    for (int kk = 0; kk < 32; ++kk) {
      const float4 wv = *(const float4*)&wl[kk][cg * 4];
#pragma unroll
      for (int i = 0; i < 8; ++i) {
        const float a = at[rg * 8 + i][kc * 32 + kk];
        acc[i][0] = fmaf(a, wv.x, acc[i][0]);
        acc[i][1] = fmaf(a, wv.y, acc[i][1]);
        acc[i][2] = fmaf(a, wv.z, acc[i][2]);
        acc[i][3] = fmaf(a, wv.w, acc[i][3]);
      }
    }
    __syncthreads();
  }
  const float4 bb = *(const float4*)&bo[cg * 4];
#pragma unroll
  for (int i = 0; i < 8; ++i) {
    float4 r;
    r.x = acc[i][0] + bb.x; r.y = acc[i][1] + bb.y;
    r.z = acc[i][2] + bb.z; r.w = acc[i][3] + bb.w;
    *(float4*)&out[(size_t)(row0 + rg * 8 + i) * DMODEL + cg * 4] = r;
  }
}

// ---------------------------------------------------------------------------
extern "C" void kernel_launch(void* const* d_in, const int* in_sizes, int n_in,
                              void* d_out, int out_size, void* d_ws, size_t ws_size,
                              hipStream_t stream)
{
  (void)in_sizes; (void)n_in; (void)out_size; (void)ws_size;
  const float* x  = (const float*)d_in[0];
  const float* Wq = (const float*)d_in[1];
  const float* bq = (const float*)d_in[2];
  const float* Wo = (const float*)d_in[3];
  const float* bo = (const float*)d_in[4];
  float* out = (float*)d_out;
  char* ws = (char*)d_ws;
  f16* qh = (f16*)(ws);                              // 2 MB
  f16* kh = (f16*)(ws + (size_t)(2 << 20));          // 2 MB
  f16* vt = (f16*)(ws + (size_t)(4 << 20));          // 2 MB (transposed V)
  float* attn = (float*)(ws + (size_t)(6 << 20));    // 4 MB

  hipLaunchKernelGGL(qkv_proj,   dim3(512), dim3(256), 0, stream, x, Wq, bq, qh, kh, vt);
  hipLaunchKernelGGL(attn_fused, dim3(512), dim3(512), 0, stream, qh, kh, vt, attn);
  hipLaunchKernelGGL(out_proj,   dim3(512), dim3(256), 0, stream, attn, Wo, bo, out);
}

// Round 12
// 150.855 us; speedup vs baseline: 1.0102x; 1.0063x over previous
//
#include <hip/hip_runtime.h>
#include <hip/hip_fp16.h>
#include <stdint.h>

typedef _Float16 f16;
typedef _Float16 half8  __attribute__((ext_vector_type(8)));
typedef _Float16 half4v __attribute__((ext_vector_type(4)));
typedef float    f32x4  __attribute__((ext_vector_type(4)));

#define NBATCH 4
#define SEQ    4096
#define DMODEL 256
#define DHEAD  64
#define NQKV   192

// ---------------------------------------------------------------------------
// Kernel A: qkv = x @ W_qkv + b_qkv (fp32 VALU). Emits:
//   qh[row][d]   fp16, pre-scaled by 1/8 (exact pow2)
//   kh[row][d]   fp16 row-major        (QK^T stages this)
//   vt[b][d][seq] fp16 transposed      (PV stages this d-major)
// ---------------------------------------------------------------------------
__global__ __launch_bounds__(256) void qkv_proj(
    const float* __restrict__ x, const float* __restrict__ Wq,
    const float* __restrict__ bq,
    f16* __restrict__ qh, f16* __restrict__ kh, f16* __restrict__ vt)
{
  __shared__ float xs[32][64];      // 8 KB
  __shared__ float wsh[64][NQKV];   // 48 KB
  const int t = threadIdx.x;
  const int row0 = blockIdx.x * 32;
  const int cg = t & 31;            // 32 col-groups x 6 cols
  const int rg = t >> 5;            // 8 row-groups x 4 rows
  const int n0 = cg * 6;
  const int m0 = rg * 4;
  float acc[4][6];
#pragma unroll
  for (int i = 0; i < 4; ++i)
#pragma unroll
    for (int j = 0; j < 6; ++j) acc[i][j] = 0.f;

  for (int kc = 0; kc < 4; ++kc) {
    const int k0 = kc * 64;
#pragma unroll
    for (int j = 0; j < 8; ++j) {
      int li = j * 256 + t;
      xs[li >> 6][li & 63] = x[(size_t)(row0 + (li >> 6)) * DMODEL + k0 + (li & 63)];
    }
#pragma unroll
    for (int j = 0; j < 48; ++j) {
      int li = j * 256 + t;
      int r = li / NQKV, c = li % NQKV;
      wsh[r][c] = Wq[(size_t)(k0 + r) * NQKV + c];
    }
    __syncthreads();
#pragma unroll
    for (int kk4 = 0; kk4 < 16; ++kk4) {
      float4 a4[4];
#pragma unroll
      for (int i = 0; i < 4; ++i) a4[i] = *(const float4*)&xs[m0 + i][kk4 * 4];
#pragma unroll
      for (int e = 0; e < 4; ++e) {
        const int kk = kk4 * 4 + e;
        float2 b01 = *(const float2*)&wsh[kk][n0];
        float2 b23 = *(const float2*)&wsh[kk][n0 + 2];
        float2 b45 = *(const float2*)&wsh[kk][n0 + 4];
#pragma unroll
        for (int i = 0; i < 4; ++i) {
          const float a = (e == 0) ? a4[i].x : (e == 1) ? a4[i].y : (e == 2) ? a4[i].z : a4[i].w;
          acc[i][0] = fmaf(a, b01.x, acc[i][0]);
          acc[i][1] = fmaf(a, b01.y, acc[i][1]);
          acc[i][2] = fmaf(a, b23.x, acc[i][2]);
          acc[i][3] = fmaf(a, b23.y, acc[i][3]);
          acc[i][4] = fmaf(a, b45.x, acc[i][4]);
          acc[i][5] = fmaf(a, b45.y, acc[i][5]);
        }
      }
    }
    __syncthreads();
  }
  const int bi  = row0 >> 12;           // batch
  const int seq0 = (row0 & (SEQ - 1)) + m0;
#pragma unroll
  for (int j = 0; j < 6; ++j) {
    const int n = n0 + j;
    const float b = bq[n];
    const float v0 = acc[0][j] + b, v1 = acc[1][j] + b;
    const float v2 = acc[2][j] + b, v3 = acc[3][j] + b;
    if (n < 64) {
      const size_t r = (size_t)row0 + m0;
      qh[(r + 0) * DHEAD + n] = (f16)(v0 * 0.125f);
      qh[(r + 1) * DHEAD + n] = (f16)(v1 * 0.125f);
      qh[(r + 2) * DHEAD + n] = (f16)(v2 * 0.125f);
      qh[(r + 3) * DHEAD + n] = (f16)(v3 * 0.125f);
    } else if (n < 128) {
      const size_t r = (size_t)row0 + m0;
      kh[(r + 0) * DHEAD + (n - 64)] = (f16)v0;
      kh[(r + 1) * DHEAD + (n - 64)] = (f16)v1;
      kh[(r + 2) * DHEAD + (n - 64)] = (f16)v2;
      kh[(r + 3) * DHEAD + (n - 64)] = (f16)v3;
    } else {
      half4v pk = {(f16)v0, (f16)v1, (f16)v2, (f16)v3};
      *(half4v*)(vt + (size_t)bi * DHEAD * SEQ + (size_t)(n - 128) * SEQ + seq0) = pk;
    }
  }
}

// ---------------------------------------------------------------------------
// Kernel B: fused scores -> threshold -> masked softmax -> PV -> OUT PROJ.
// Main body = R7 verified template (16 q-rows/block, 8 waves, global_load_lds
// dbuf, counted vmcnt(4), SCHED_PIN before in-loop stage issue; VGPR 112 — no
// spill). R12 addition: out-projection fused into the epilogue — O/z goes to
// LDS obuf, W_out staged fp16 into the dead stage region, each thread emits 8
// final out columns. Kernel C removed (saves launch + 8 MB intermediate).
// ---------------------------------------------------------------------------
#define WAVES  8
#define CHUNK  32
#define NCHUNK 16
#define BUFH   2048    // halves per buffer (4 KB = 32 rows x 64 halves)

__device__ __forceinline__ int khash(int row) {   // bijective per permuted tile
  return ((row >> 2) & 6) | ((row >> 1) & 1);
}

typedef __attribute__((address_space(3))) f16 as3_f16;
typedef __attribute__((address_space(1))) const f16 as1_f16;

__device__ __forceinline__ void gll16(const f16* g, f16* l) {
  __builtin_amdgcn_global_load_lds((as1_f16*)g, (as3_f16*)l, 16, 0, 0);
}

#define SCHED_PIN __builtin_amdgcn_sched_barrier(0)
#define WAITVM4 do { asm volatile("s_waitcnt vmcnt(4)" ::: "memory"); \
                     __builtin_amdgcn_sched_barrier(0); } while (0)
#define WAITVM0 do { asm volatile("s_waitcnt vmcnt(0)" ::: "memory"); \
                     __builtin_amdgcn_sched_barrier(0); } while (0)

// K chunk -> LDS[row 0..31][slot 0..7], source slot pre-XOR'd with khash(row)
__device__ __forceinline__ void stage_k(const f16* kchunk, f16* buf, int l) {
#pragma unroll
  for (int i = 0; i < 4; ++i) {
    const int row = i * 8 + (l >> 3);
    const int c8 = (l & 7) ^ khash(row);
    gll16(kchunk + row * DHEAD + c8 * 8, buf + i * 512);
  }
}

// V chunk -> LDS rows = d&31 (128 B), slots 0..3 = d<32, 4..7 = d>=32, XOR r&7
__device__ __forceinline__ void stage_v(const f16* vchunk, f16* buf, int l) {
#pragma unroll
  for (int i = 0; i < 4; ++i) {
    const int r = i * 8 + (l >> 3);
    const int jj = (l & 7) ^ (r & 7);
    const int d = ((jj >> 2) << 5) + r;
    const int kb = jj & 3;
    gll16(vchunk + (size_t)d * SEQ + kb * 8, buf + i * 512);
  }
}

#define WROW 264   // whs row stride in halves (528 B, 16B-aligned)

__global__ __launch_bounds__(512) void attn_fused(
    const f16* __restrict__ qh, const f16* __restrict__ kh,
    const f16* __restrict__ vt, const float* __restrict__ Wo,
    const float* __restrict__ bo, float* __restrict__ out)
{
  __shared__ f16 stage[WAVES][2 * BUFH];     // 64 KB: per-wave double buffer
  __shared__ float selbuf[2][WAVES][16];
  __shared__ float zrow[16];
  __shared__ float obuf[16 * 68];            // 4.35 KB: O rows (post-division)

  const int tid = threadIdx.x;
  const int w = tid >> 6;
  const int l = tid & 63;
  const int qr = l & 15;
  const int g  = l >> 4;
  const int bi = blockIdx.x >> 8;
  const int rb = blockIdx.x & 255;
  const size_t qrow0  = (size_t)bi * SEQ + (size_t)rb * 16;
  const size_t kvbase = (size_t)bi * SEQ * DHEAD;
  const int key0 = w * (CHUNK * NCHUNK);

  f16* const mybuf = &stage[w][0];

  // Q fragments (B operand), q pre-scaled by 1/8 in qh.
  half8 qf0, qf1;
  {
    const f16* qp = qh + (qrow0 + qr) * DHEAD;
    qf0 = *(const half8*)(qp + 8 * g);
    qf1 = *(const half8*)(qp + 32 + 8 * g);
  }

  half4v P[2 * NCHUNK];   // P[2kc+kt][r] = S[qr][32kc + 8g + 4kt + r]
  float mn = 1e30f, mx = -1e30f;

  // ---- QK^T: async pipeline, no barriers ----
  const f16* kc0 = kh + kvbase + (size_t)key0 * DHEAD;
  stage_k(kc0, mybuf, l);
  stage_k(kc0 + 32 * DHEAD, mybuf + BUFH, l);
#pragma unroll
  for (int kc = 0; kc < NCHUNK; ++kc) {
    if (kc < NCHUNK - 1) { WAITVM4; } else { WAITVM0; }
    const f16* bufp = mybuf + (kc & 1) * BUFH;
#pragma unroll
    for (int kt = 0; kt < 2; ++kt) {
      const int rowk = 8 * (qr >> 2) + 4 * kt + (qr & 3);   // permuted key row
      const int h = khash(rowk);
      f32x4 c = {0.f, 0.f, 0.f, 0.f};
      half8 kf0 = *(const half8*)(bufp + rowk * DHEAD + ((g ^ h) * 8));
      c = __builtin_amdgcn_mfma_f32_16x16x32_f16(kf0, qf0, c, 0, 0, 0);
      half8 kf1 = *(const half8*)(bufp + rowk * DHEAD + (((4 + g) ^ h) * 8));
      c = __builtin_amdgcn_mfma_f32_16x16x32_f16(kf1, qf1, c, 0, 0, 0);
      mn = fminf(mn, fminf(fminf(c[0], c[1]), fminf(c[2], c[3])));
      mx = fmaxf(mx, fmaxf(fmaxf(c[0], c[1]), fmaxf(c[2], c[3])));
      P[kc * 2 + kt] = (half4v){(f16)c[0], (f16)c[1], (f16)c[2], (f16)c[3]};
    }
    if (kc + 2 < NCHUNK) {
      SCHED_PIN;   // all reads of buf[kc&1] complete (in-order DS) before DMA
      stage_k(kc0 + (size_t)(kc + 2) * 32 * DHEAD, mybuf + (kc & 1) * BUFH, l);
    }
  }

  // ---- per-row min/max across lanes and waves ----
  mn = fminf(mn, __shfl_xor(mn, 16, 64));
  mn = fminf(mn, __shfl_xor(mn, 32, 64));
  mx = fmaxf(mx, __shfl_xor(mx, 16, 64));
  mx = fmaxf(mx, __shfl_xor(mx, 32, 64));
  if (l < 16) { selbuf[0][w][l] = mn; selbuf[1][w][l] = mx; }
  __syncthreads();
  float lo = 1e30f, hi = -1e30f;
#pragma unroll
  for (int j = 0; j < WAVES; ++j) {
    lo = fminf(lo, selbuf[0][j][qr]);
    hi = fmaxf(hi, selbuf[1][j][qr]);
  }
  __syncthreads();   // lo/hi reads done before iter 0 overwrites selbuf[0]

  // ---- bisection on sampled count (1024 of 4096; target 512) ----
#pragma unroll
  for (int it = 0; it < 10; ++it) {
    const float tm = 0.5f * (lo + hi);
    const f16 th = (f16)tm;
    int cnt = 0;
#pragma unroll
    for (int j = 0; j < 2 * NCHUNK; j += 4) {
      half4v s = P[j];
      cnt += (s[0] >= th) + (s[1] >= th) + (s[2] >= th) + (s[3] >= th);
    }
    cnt += __shfl_xor(cnt, 16, 64);
    cnt += __shfl_xor(cnt, 32, 64);
    if (l < 16) selbuf[it & 1][w][l] = (float)cnt;
    __syncthreads();
    float tot = 0.f;
#pragma unroll
    for (int j = 0; j < WAVES; ++j) tot += selbuf[it & 1][j][qr];
    if (tot >= 512.f) lo = tm; else hi = tm;
  }
  const float thr = lo;

  // ---- prefetch V chunks 0/1 (exp loop + z-barrier hide the latency) ----
  const f16* vchunk0 = vt + (size_t)bi * DHEAD * SEQ + key0;
  stage_v(vchunk0, mybuf, l);
  stage_v(vchunk0 + 32, mybuf + BUFH, l);

  // ---- exp in place (masked -> exp(0)=1, matches softmax(scores*mask)) ----
  float z = 0.f;
#pragma unroll
  for (int j = 0; j < 2 * NCHUNK; ++j) {
    half4v s = P[j];
    float p0 = (float)s[0], p1 = (float)s[1], p2 = (float)s[2], p3 = (float)s[3];
    p0 = (p0 >= thr) ? __expf(p0) : 1.f;
    p1 = (p1 >= thr) ? __expf(p1) : 1.f;
    p2 = (p2 >= thr) ? __expf(p2) : 1.f;
    p3 = (p3 >= thr) ? __expf(p3) : 1.f;
    z += (p0 + p1) + (p2 + p3);
    P[j] = (half4v){(f16)p0, (f16)p1, (f16)p2, (f16)p3};
  }
  z += __shfl_xor(z, 16, 64);
  z += __shfl_xor(z, 32, 64);
  if (l < 16) selbuf[0][w][l] = z;
  __syncthreads();
  if (w == 0 && l < 16) {
    float t2 = 0.f;
#pragma unroll
    for (int j = 0; j < WAVES; ++j) t2 += selbuf[0][j][l];
    zrow[l] = t2;   // consumed after the post-PV barrier
  }

  // ---- PV: O^T = V^T P^T; A = V^T (b128 LDS reads), B = P register concat ----
  f32x4 acc[4];
#pragma unroll
  for (int p = 0; p < 4; ++p) acc[p] = (f32x4){0.f, 0.f, 0.f, 0.f};

#pragma unroll
  for (int kc = 0; kc < NCHUNK; ++kc) {
    if (kc < NCHUNK - 1) { WAITVM4; } else { WAITVM0; }
    const f16* bufp = mybuf + (kc & 1) * BUFH;
    const half8 pb = __builtin_shufflevector(P[kc * 2], P[kc * 2 + 1],
                                             0, 1, 2, 3, 4, 5, 6, 7);
#pragma unroll
    for (int pnl = 0; pnl < 4; ++pnl) {
      const int d = 16 * pnl + qr;
      const int r = d & 31;
      const int j = (((d >> 5) << 2) + g) ^ (r & 7);
      half8 va = *(const half8*)(bufp + r * 64 + j * 8);
      acc[pnl] = __builtin_amdgcn_mfma_f32_16x16x32_f16(va, pb, acc[pnl], 0, 0, 0);
    }
    if (kc + 2 < NCHUNK) {
      SCHED_PIN;   // all reads of buf[kc&1] complete (in-order DS) before DMA
      stage_v(vchunk0 + (kc + 2) * 32, mybuf + (kc & 1) * BUFH, l);
    }
  }

  // ---- cross-wave reduce -> obuf (O/z), 68-pad rows ----
  float* red = (float*)mybuf;   // 16 rows x 68 floats = 4352 B per wave region
#pragma unroll
  for (int pnl = 0; pnl < 4; ++pnl)
    *(f32x4*)&red[qr * 68 + pnl * 16 + 4 * g] = acc[pnl];
  __syncthreads();
#pragma unroll
  for (int oo = 0; oo < 2; ++oo) {
    const int o = tid * 2 + oo;
    const int i = o >> 6, n = o & 63;
    float s = 0.f;
#pragma unroll
    for (int j = 0; j < WAVES; ++j) s += ((const float*)&stage[j][0])[i * 68 + n];
    obuf[i * 68 + n] = s / zrow[i];
  }
  __syncthreads();   // red regions dead; stage area reusable for W

  // ---- stage W_out as fp16 into (dead) stage region: [64][WROW] halves ----
  f16* whs = &stage[0][0];   // 64*WROW*2 = 33.8 KB <= 64 KB
  {
    const int kr = tid >> 3;            // 0..63
    const int c0 = (tid & 7) * 32;      // 8 x 32-col chunks
    const float* wsrc = Wo + (size_t)kr * DMODEL + c0;
    f16* wdst = whs + kr * WROW + c0;
#pragma unroll
    for (int q = 0; q < 4; ++q) {
      float4 aa = *(const float4*)(wsrc + q * 8);
      float4 bb2 = *(const float4*)(wsrc + q * 8 + 4);
      half8 hv = {(f16)aa.x, (f16)aa.y, (f16)aa.z, (f16)aa.w,
                  (f16)bb2.x, (f16)bb2.y, (f16)bb2.z, (f16)bb2.w};
      *(half8*)(wdst + q * 8) = hv;
    }
  }
  __syncthreads();

  // ---- out[i][c0..c0+8] = obuf[i][:] . W[:, c0..c0+8] + bo ----
  {
    const int i2 = tid >> 5;            // 0..15
    const int c0 = (tid & 31) * 8;      // 32 col-groups x 8 cols
    float accoA[4], accoB[4];
    {
      float4 b0 = *(const float4*)(bo + c0);
      float4 b1 = *(const float4*)(bo + c0 + 4);
      accoA[0] = b0.x; accoA[1] = b0.y; accoA[2] = b0.z; accoA[3] = b0.w;
      accoB[0] = b1.x; accoB[1] = b1.y; accoB[2] = b1.z; accoB[3] = b1.w;
    }
    const float* orow = &obuf[i2 * 68];
#pragma unroll
    for (int k = 0; k < DHEAD; ++k) {
      const float a = orow[k];          // broadcast across 32 lanes
      half8 w8 = *(const half8*)(whs + k * WROW + c0);
      accoA[0] = fmaf(a, (float)w8[0], accoA[0]);
      accoA[1] = fmaf(a, (float)w8[1], accoA[1]);
      accoA[2] = fmaf(a, (float)w8[2], accoA[2]);
      accoA[3] = fmaf(a, (float)w8[3], accoA[3]);
      accoB[0] = fmaf(a, (float)w8[4], accoB[0]);
      accoB[1] = fmaf(a, (float)w8[5], accoB[1]);
      accoB[2] = fmaf(a, (float)w8[6], accoB[2]);
      accoB[3] = fmaf(a, (float)w8[7], accoB[3]);
    }
    float* op = out + (qrow0 + i2) * DMODEL + c0;
    *(float4*)op = (float4){accoA[0], accoA[1], accoA[2], accoA[3]};
    *(float4*)(op + 4) = (float4){accoB[0], accoB[1], accoB[2], accoB[3]};
  }
}

// ---------------------------------------------------------------------------
extern "C" void kernel_launch(void* const* d_in, const int* in_sizes, int n_in,
                              void* d_out, int out_size, void* d_ws, size_t ws_size,
                              hipStream_t stream)
{
  (void)in_sizes; (void)n_in; (void)out_size; (void)ws_size;
  const float* x  = (const float*)d_in[0];
  const float* Wq = (const float*)d_in[1];
  const float* bq = (const float*)d_in[2];
  const float* Wo = (const float*)d_in[3];
  const float* bo = (const float*)d_in[4];
  float* out = (float*)d_out;
  char* ws = (char*)d_ws;
  f16* qh = (f16*)(ws);                              // 2 MB
  f16* kh = (f16*)(ws + (size_t)(2 << 20));          // 2 MB
  f16* vt = (f16*)(ws + (size_t)(4 << 20));          // 2 MB (transposed V)

  hipLaunchKernelGGL(qkv_proj,   dim3(512),  dim3(256), 0, stream, x, Wq, bq, qh, kh, vt);
  hipLaunchKernelGGL(attn_fused, dim3(1024), dim3(512), 0, stream, qh, kh, vt, Wo, bo, out);
}

// Round 13
// 132.518 us; speedup vs baseline: 1.1499x; 1.1384x over previous
//
#include <hip/hip_runtime.h>
#include <hip/hip_fp16.h>
#include <stdint.h>

typedef _Float16 f16;
typedef _Float16 half8  __attribute__((ext_vector_type(8)));
typedef _Float16 half4v __attribute__((ext_vector_type(4)));
typedef float    f32x4  __attribute__((ext_vector_type(4)));

#define NBATCH 4
#define SEQ    4096
#define DMODEL 256
#define DHEAD  64
#define NQKV   192

// ---------------------------------------------------------------------------
// Kernel A: qkv = x @ W_qkv + b_qkv (fp32 VALU). Emits:
//   qh[row][d]   fp16, pre-scaled by 1/8 (exact pow2)
//   kh[row][d]   fp16 row-major        (QK^T stages this)
//   vt[b][d][seq] fp16 transposed      (PV stages this d-major)
//   wt[c][k]     fp16 W_out^T (blocks 0..15 tail) for attn's fused out-proj
// ---------------------------------------------------------------------------
__global__ __launch_bounds__(256) void qkv_proj(
    const float* __restrict__ x, const float* __restrict__ Wq,
    const float* __restrict__ bq, const float* __restrict__ Wo,
    f16* __restrict__ qh, f16* __restrict__ kh, f16* __restrict__ vt,
    f16* __restrict__ wt)
{
  __shared__ float xs[32][64];      // 8 KB
  __shared__ float wsh[64][NQKV];   // 48 KB
  const int t = threadIdx.x;
  const int row0 = blockIdx.x * 32;
  const int cg = t & 31;            // 32 col-groups x 6 cols
  const int rg = t >> 5;            // 8 row-groups x 4 rows
  const int n0 = cg * 6;
  const int m0 = rg * 4;
  float acc[4][6];
#pragma unroll
  for (int i = 0; i < 4; ++i)
#pragma unroll
    for (int j = 0; j < 6; ++j) acc[i][j] = 0.f;

  for (int kc = 0; kc < 4; ++kc) {
    const int k0 = kc * 64;
#pragma unroll
    for (int j = 0; j < 8; ++j) {
      int li = j * 256 + t;
      xs[li >> 6][li & 63] = x[(size_t)(row0 + (li >> 6)) * DMODEL + k0 + (li & 63)];
    }
#pragma unroll
    for (int j = 0; j < 48; ++j) {
      int li = j * 256 + t;
      int r = li / NQKV, c = li % NQKV;
      wsh[r][c] = Wq[(size_t)(k0 + r) * NQKV + c];
    }
    __syncthreads();
#pragma unroll
    for (int kk4 = 0; kk4 < 16; ++kk4) {
      float4 a4[4];
#pragma unroll
      for (int i = 0; i < 4; ++i) a4[i] = *(const float4*)&xs[m0 + i][kk4 * 4];
#pragma unroll
      for (int e = 0; e < 4; ++e) {
        const int kk = kk4 * 4 + e;
        float2 b01 = *(const float2*)&wsh[kk][n0];
        float2 b23 = *(const float2*)&wsh[kk][n0 + 2];
        float2 b45 = *(const float2*)&wsh[kk][n0 + 4];
#pragma unroll
        for (int i = 0; i < 4; ++i) {
          const float a = (e == 0) ? a4[i].x : (e == 1) ? a4[i].y : (e == 2) ? a4[i].z : a4[i].w;
          acc[i][0] = fmaf(a, b01.x, acc[i][0]);
          acc[i][1] = fmaf(a, b01.y, acc[i][1]);
          acc[i][2] = fmaf(a, b23.x, acc[i][2]);
          acc[i][3] = fmaf(a, b23.y, acc[i][3]);
          acc[i][4] = fmaf(a, b45.x, acc[i][4]);
          acc[i][5] = fmaf(a, b45.y, acc[i][5]);
        }
      }
    }
    __syncthreads();
  }
  const int bi  = row0 >> 12;           // batch
  const int seq0 = (row0 & (SEQ - 1)) + m0;
#pragma unroll
  for (int j = 0; j < 6; ++j) {
    const int n = n0 + j;
    const float b = bq[n];
    const float v0 = acc[0][j] + b, v1 = acc[1][j] + b;
    const float v2 = acc[2][j] + b, v3 = acc[3][j] + b;
    if (n < 64) {
      const size_t r = (size_t)row0 + m0;
      qh[(r + 0) * DHEAD + n] = (f16)(v0 * 0.125f);
      qh[(r + 1) * DHEAD + n] = (f16)(v1 * 0.125f);
      qh[(r + 2) * DHEAD + n] = (f16)(v2 * 0.125f);
      qh[(r + 3) * DHEAD + n] = (f16)(v3 * 0.125f);
    } else if (n < 128) {
      const size_t r = (size_t)row0 + m0;
      kh[(r + 0) * DHEAD + (n - 64)] = (f16)v0;
      kh[(r + 1) * DHEAD + (n - 64)] = (f16)v1;
      kh[(r + 2) * DHEAD + (n - 64)] = (f16)v2;
      kh[(r + 3) * DHEAD + (n - 64)] = (f16)v3;
    } else {
      half4v pk = {(f16)v0, (f16)v1, (f16)v2, (f16)v3};
      *(half4v*)(vt + (size_t)bi * DHEAD * SEQ + (size_t)(n - 128) * SEQ + seq0) = pk;
    }
  }
  // ---- tail: blocks 0..15 emit W_out^T fp16 (wt[c][k], c=0..255, k=0..63) ----
  if (blockIdx.x < 16) {
    const int gid = blockIdx.x * 256 + t;   // 0..4095
    const int c = gid & 255;
    const int k0 = (gid >> 8) * 4;          // 0..60
    half4v wv = {(f16)Wo[(size_t)(k0 + 0) * DMODEL + c],
                 (f16)Wo[(size_t)(k0 + 1) * DMODEL + c],
                 (f16)Wo[(size_t)(k0 + 2) * DMODEL + c],
                 (f16)Wo[(size_t)(k0 + 3) * DMODEL + c]};
    *(half4v*)(wt + (size_t)c * DHEAD + k0) = wv;
  }
}

// ---------------------------------------------------------------------------
// Kernel B: fused scores -> threshold -> masked softmax -> PV -> OUT PROJ.
// Main body = R7 verified template (16 q-rows/block, 8 waves, global_load_lds
// dbuf, counted vmcnt(4), SCHED_PIN before in-loop stage issue; VGPR ~112).
// R13: out-proj epilogue via MFMA (O fp16 A-frags from obuf; W^T fp16 staged
// from wt with source-side XOR swizzle; bias in acc init). Replaces R12's
// 1100-VALU-inst scalar loop with ~8 MFMA + ~40 mem ops per thread.
// ---------------------------------------------------------------------------
#define WAVES  8
#define CHUNK  32
#define NCHUNK 16
#define BUFH   2048    // halves per buffer (4 KB = 32 rows x 64 halves)

__device__ __forceinline__ int khash(int row) {   // bijective per permuted tile
  return ((row >> 2) & 6) | ((row >> 1) & 1);
}

typedef __attribute__((address_space(3))) f16 as3_f16;
typedef __attribute__((address_space(1))) const f16 as1_f16;

__device__ __forceinline__ void gll16(const f16* g, f16* l) {
  __builtin_amdgcn_global_load_lds((as1_f16*)g, (as3_f16*)l, 16, 0, 0);
}

#define SCHED_PIN __builtin_amdgcn_sched_barrier(0)
#define WAITVM4 do { asm volatile("s_waitcnt vmcnt(4)" ::: "memory"); \
                     __builtin_amdgcn_sched_barrier(0); } while (0)
#define WAITVM0 do { asm volatile("s_waitcnt vmcnt(0)" ::: "memory"); \
                     __builtin_amdgcn_sched_barrier(0); } while (0)

// K chunk -> LDS[row 0..31][slot 0..7], source slot pre-XOR'd with khash(row)
__device__ __forceinline__ void stage_k(const f16* kchunk, f16* buf, int l) {
#pragma unroll
  for (int i = 0; i < 4; ++i) {
    const int row = i * 8 + (l >> 3);
    const int c8 = (l & 7) ^ khash(row);
    gll16(kchunk + row * DHEAD + c8 * 8, buf + i * 512);
  }
}

// V chunk -> LDS rows = d&31 (128 B), slots 0..3 = d<32, 4..7 = d>=32, XOR r&7
__device__ __forceinline__ void stage_v(const f16* vchunk, f16* buf, int l) {
#pragma unroll
  for (int i = 0; i < 4; ++i) {
    const int r = i * 8 + (l >> 3);
    const int jj = (l & 7) ^ (r & 7);
    const int d = ((jj >> 2) << 5) + r;
    const int kb = jj & 3;
    gll16(vchunk + (size_t)d * SEQ + kb * 8, buf + i * 512);
  }
}

__global__ __launch_bounds__(512) void attn_fused(
    const f16* __restrict__ qh, const f16* __restrict__ kh,
    const f16* __restrict__ vt, const f16* __restrict__ wt,
    const float* __restrict__ bo, float* __restrict__ out)
{
  __shared__ f16 stage[WAVES][2 * BUFH];     // 64 KB: per-wave double buffer
  __shared__ float selbuf[2][WAVES][16];
  __shared__ float zrow[16];
  __shared__ float obuf[16 * 68];            // 4.35 KB: O rows (post-division)

  const int tid = threadIdx.x;
  const int w = tid >> 6;
  const int l = tid & 63;
  const int qr = l & 15;
  const int g  = l >> 4;
  const int bi = blockIdx.x >> 8;
  const int rb = blockIdx.x & 255;
  const size_t qrow0  = (size_t)bi * SEQ + (size_t)rb * 16;
  const size_t kvbase = (size_t)bi * SEQ * DHEAD;
  const int key0 = w * (CHUNK * NCHUNK);

  f16* const mybuf = &stage[w][0];

  // Q fragments (B operand), q pre-scaled by 1/8 in qh.
  half8 qf0, qf1;
  {
    const f16* qp = qh + (qrow0 + qr) * DHEAD;
    qf0 = *(const half8*)(qp + 8 * g);
    qf1 = *(const half8*)(qp + 32 + 8 * g);
  }

  half4v P[2 * NCHUNK];   // P[2kc+kt][r] = S[qr][32kc + 8g + 4kt + r]
  float mn = 1e30f, mx = -1e30f;

  // ---- QK^T: async pipeline, no barriers ----
  const f16* kc0 = kh + kvbase + (size_t)key0 * DHEAD;
  stage_k(kc0, mybuf, l);
  stage_k(kc0 + 32 * DHEAD, mybuf + BUFH, l);
#pragma unroll
  for (int kc = 0; kc < NCHUNK; ++kc) {
    if (kc < NCHUNK - 1) { WAITVM4; } else { WAITVM0; }
    const f16* bufp = mybuf + (kc & 1) * BUFH;
#pragma unroll
    for (int kt = 0; kt < 2; ++kt) {
      const int rowk = 8 * (qr >> 2) + 4 * kt + (qr & 3);   // permuted key row
      const int h = khash(rowk);
      f32x4 c = {0.f, 0.f, 0.f, 0.f};
      half8 kf0 = *(const half8*)(bufp + rowk * DHEAD + ((g ^ h) * 8));
      c = __builtin_amdgcn_mfma_f32_16x16x32_f16(kf0, qf0, c, 0, 0, 0);
      half8 kf1 = *(const half8*)(bufp + rowk * DHEAD + (((4 + g) ^ h) * 8));
      c = __builtin_amdgcn_mfma_f32_16x16x32_f16(kf1, qf1, c, 0, 0, 0);
      mn = fminf(mn, fminf(fminf(c[0], c[1]), fminf(c[2], c[3])));
      mx = fmaxf(mx, fmaxf(fmaxf(c[0], c[1]), fmaxf(c[2], c[3])));
      P[kc * 2 + kt] = (half4v){(f16)c[0], (f16)c[1], (f16)c[2], (f16)c[3]};
    }
    if (kc + 2 < NCHUNK) {
      SCHED_PIN;   // all reads of buf[kc&1] complete (in-order DS) before DMA
      stage_k(kc0 + (size_t)(kc + 2) * 32 * DHEAD, mybuf + (kc & 1) * BUFH, l);
    }
  }

  // ---- per-row min/max across lanes and waves ----
  mn = fminf(mn, __shfl_xor(mn, 16, 64));
  mn = fminf(mn, __shfl_xor(mn, 32, 64));
  mx = fmaxf(mx, __shfl_xor(mx, 16, 64));
  mx = fmaxf(mx, __shfl_xor(mx, 32, 64));
  if (l < 16) { selbuf[0][w][l] = mn; selbuf[1][w][l] = mx; }
  __syncthreads();
  float lo = 1e30f, hi = -1e30f;
#pragma unroll
  for (int j = 0; j < WAVES; ++j) {
    lo = fminf(lo, selbuf[0][j][qr]);
    hi = fmaxf(hi, selbuf[1][j][qr]);
  }
  __syncthreads();   // lo/hi reads done before iter 0 overwrites selbuf[0]

  // ---- bisection on sampled count (1024 of 4096; target 512) ----
#pragma unroll
  for (int it = 0; it < 10; ++it) {
    const float tm = 0.5f * (lo + hi);
    const f16 th = (f16)tm;
    int cnt = 0;
#pragma unroll
    for (int j = 0; j < 2 * NCHUNK; j += 4) {
      half4v s = P[j];
      cnt += (s[0] >= th) + (s[1] >= th) + (s[2] >= th) + (s[3] >= th);
    }
    cnt += __shfl_xor(cnt, 16, 64);
    cnt += __shfl_xor(cnt, 32, 64);
    if (l < 16) selbuf[it & 1][w][l] = (float)cnt;
    __syncthreads();
    float tot = 0.f;
#pragma unroll
    for (int j = 0; j < WAVES; ++j) tot += selbuf[it & 1][j][qr];
    if (tot >= 512.f) lo = tm; else hi = tm;
  }
  const float thr = lo;

  // ---- prefetch V chunks 0/1 (exp loop + z-barrier hide the latency) ----
  const f16* vchunk0 = vt + (size_t)bi * DHEAD * SEQ + key0;
  stage_v(vchunk0, mybuf, l);
  stage_v(vchunk0 + 32, mybuf + BUFH, l);

  // ---- exp in place (masked -> exp(0)=1, matches softmax(scores*mask)) ----
  float z = 0.f;
#pragma unroll
  for (int j = 0; j < 2 * NCHUNK; ++j) {
    half4v s = P[j];
    float p0 = (float)s[0], p1 = (float)s[1], p2 = (float)s[2], p3 = (float)s[3];
    p0 = (p0 >= thr) ? __expf(p0) : 1.f;
    p1 = (p1 >= thr) ? __expf(p1) : 1.f;
    p2 = (p2 >= thr) ? __expf(p2) : 1.f;
    p3 = (p3 >= thr) ? __expf(p3) : 1.f;
    z += (p0 + p1) + (p2 + p3);
    P[j] = (half4v){(f16)p0, (f16)p1, (f16)p2, (f16)p3};
  }
  z += __shfl_xor(z, 16, 64);
  z += __shfl_xor(z, 32, 64);
  if (l < 16) selbuf[0][w][l] = z;
  __syncthreads();
  if (w == 0 && l < 16) {
    float t2 = 0.f;
#pragma unroll
    for (int j = 0; j < WAVES; ++j) t2 += selbuf[0][j][l];
    zrow[l] = t2;   // consumed after the post-PV barrier
  }

  // ---- PV: O^T = V^T P^T; A = V^T (b128 LDS reads), B = P register concat ----
  f32x4 acc[4];
#pragma unroll
  for (int p = 0; p < 4; ++p) acc[p] = (f32x4){0.f, 0.f, 0.f, 0.f};

#pragma unroll
  for (int kc = 0; kc < NCHUNK; ++kc) {
    if (kc < NCHUNK - 1) { WAITVM4; } else { WAITVM0; }
    const f16* bufp = mybuf + (kc & 1) * BUFH;
    const half8 pb = __builtin_shufflevector(P[kc * 2], P[kc * 2 + 1],
                                             0, 1, 2, 3, 4, 5, 6, 7);
#pragma unroll
    for (int pnl = 0; pnl < 4; ++pnl) {
      const int d = 16 * pnl + qr;
      const int r = d & 31;
      const int j = (((d >> 5) << 2) + g) ^ (r & 7);
      half8 va = *(const half8*)(bufp + r * 64 + j * 8);
      acc[pnl] = __builtin_amdgcn_mfma_f32_16x16x32_f16(va, pb, acc[pnl], 0, 0, 0);
    }
    if (kc + 2 < NCHUNK) {
      SCHED_PIN;   // all reads of buf[kc&1] complete (in-order DS) before DMA
      stage_v(vchunk0 + (kc + 2) * 32, mybuf + (kc & 1) * BUFH, l);
    }
  }

  // ---- cross-wave reduce -> obuf (O/z), 68-pad rows ----
  float* red = (float*)mybuf;   // 16 rows x 68 floats = 4352 B per wave region
#pragma unroll
  for (int pnl = 0; pnl < 4; ++pnl)
    *(f32x4*)&red[qr * 68 + pnl * 16 + 4 * g] = acc[pnl];
  __syncthreads();
#pragma unroll
  for (int oo = 0; oo < 2; ++oo) {
    const int o = tid * 2 + oo;
    const int i = o >> 6, n = o & 63;
    float s = 0.f;
#pragma unroll
    for (int j = 0; j < WAVES; ++j) s += ((const float*)&stage[j][0])[i * 68 + n];
    obuf[i * 68 + n] = s / zrow[i];
  }
  __syncthreads();   // red reads done (stage reusable); obuf visible to all

  // ---- stage wt (W^T fp16) into stage[0..32KB]: wave w -> rows 32w..32w+31,
  // LDS linear, source block pre-XOR'd with (c&7) ----
  f16* const wl = &stage[0][0];
#pragma unroll
  for (int i = 0; i < 4; ++i) {
    const int c = (w * 4 + i) * 8 + (l >> 3);
    const int blk = (l & 7) ^ (c & 7);
    gll16(wt + (size_t)c * DHEAD + blk * 8, wl + (w * 4 + i) * 512);
  }
  WAITVM0;   // wave-local: wave w reads only rows it staged

  // ---- out = O @ W^T + bo via MFMA: wave w owns col tiles nt = 2w, 2w+1 ----
  half4v ofr[4];
#pragma unroll
  for (int pnl = 0; pnl < 4; ++pnl) {
    f32x4 o4 = *(const f32x4*)&obuf[qr * 68 + pnl * 16 + 4 * g];
    ofr[pnl] = (half4v){(f16)o4[0], (f16)o4[1], (f16)o4[2], (f16)o4[3]};
  }
#pragma unroll
  for (int nt2 = 0; nt2 < 2; ++nt2) {
    const int nt = w * 2 + nt2;
    const int c = 16 * nt + qr;             // output column
    const float bv = bo[c];
    f32x4 ao = {bv, bv, bv, bv};
#pragma unroll
    for (int pnl = 0; pnl < 4; ++pnl) {
      const int blk = 2 * pnl + (g >> 1);   // k-block = (16pnl+4g)>>3
      half4v wf = *(const half4v*)(wl + c * DHEAD + ((blk ^ (c & 7)) * 8) + (g & 1) * 4);
      ao = __builtin_amdgcn_mfma_f32_16x16x16f16(ofr[pnl], wf, ao, 0, 0, 0);
    }
    float* op = out + (qrow0 + 4 * g) * DMODEL + c;
#pragma unroll
    for (int r = 0; r < 4; ++r) op[r * DMODEL] = ao[r];
  }
}

// ---------------------------------------------------------------------------
extern "C" void kernel_launch(void* const* d_in, const int* in_sizes, int n_in,
                              void* d_out, int out_size, void* d_ws, size_t ws_size,
                              hipStream_t stream)
{
  (void)in_sizes; (void)n_in; (void)out_size; (void)ws_size;
  const float* x  = (const float*)d_in[0];
  const float* Wq = (const float*)d_in[1];
  const float* bq = (const float*)d_in[2];
  const float* Wo = (const float*)d_in[3];
  const float* bo = (const float*)d_in[4];
  float* out = (float*)d_out;
  char* ws = (char*)d_ws;
  f16* qh = (f16*)(ws);                              // 2 MB
  f16* kh = (f16*)(ws + (size_t)(2 << 20));          // 2 MB
  f16* vt = (f16*)(ws + (size_t)(4 << 20));          // 2 MB (transposed V)
  f16* wt = (f16*)(ws + (size_t)(6 << 20));          // 32 KB (W_out^T fp16)

  hipLaunchKernelGGL(qkv_proj,   dim3(512),  dim3(256), 0, stream, x, Wq, bq, Wo, qh, kh, vt, wt);
  hipLaunchKernelGGL(attn_fused, dim3(1024), dim3(512), 0, stream, qh, kh, vt, wt, bo, out);
}

// Round 14
// 112.531 us; speedup vs baseline: 1.3542x; 1.1776x over previous
//
#include <hip/hip_runtime.h>
#include <hip/hip_fp16.h>
#include <stdint.h>

typedef _Float16 f16;
typedef _Float16 half8  __attribute__((ext_vector_type(8)));
typedef _Float16 half4v __attribute__((ext_vector_type(4)));
typedef float    f32x4  __attribute__((ext_vector_type(4)));

#define NBATCH 4
#define SEQ    4096
#define DMODEL 256
#define DHEAD  64
#define NQKV   192

// ---------------------------------------------------------------------------
// Kernel A (R14): qkv = x @ W_qkv + b_qkv via MFMA (fp16 in, fp32 acc).
// 64 rows/block, 4 waves x one 16-row m-tile. x staged fp16 [64][272];
// W_qkv chunk staged fp16-transposed [192][40], double-buffered.
// q/k: mfma(A=W^T, B=x) -> lane owns one seq row, 4 contiguous d.
// v:   mfma(A=x, B=W)  -> lane owns one d, 4 contiguous seq (vt layout).
// Tail (blocks 0..15): W_out^T fp16 for attn's fused out-proj (as R13).
// ---------------------------------------------------------------------------
#define XSP 272
#define WQP 40

__device__ __forceinline__ void stage_w(const float* __restrict__ Wq,
                                        f16* dst, int kk, int t) {
#pragma unroll
  for (int uu = 0; uu < 3; ++uu) {
    const int u = uu * 256 + t;       // 0..767 16B-units
    const int n = u >> 2;             // 0..191
    const int kc8 = u & 3;
    const int k0 = kk * 32 + kc8 * 8;
    half8 hv;
#pragma unroll
    for (int e = 0; e < 8; ++e) hv[e] = (f16)Wq[(size_t)(k0 + e) * NQKV + n];
    *(half8*)(dst + n * WQP + kc8 * 8) = hv;
  }
}

__global__ __launch_bounds__(256) void qkv_mfma(
    const float* __restrict__ x, const float* __restrict__ Wq,
    const float* __restrict__ bq, const float* __restrict__ Wo,
    f16* __restrict__ qh, f16* __restrict__ kh, f16* __restrict__ vt,
    f16* __restrict__ wt)
{
  __shared__ f16 xs[64 * XSP];          // 34816 B
  __shared__ f16 wql[2][192 * WQP];     // 30720 B  (total 64 KB)
  const int t = threadIdx.x;
  const int w = t >> 6;
  const int l = t & 63;
  const int qr = l & 15;
  const int g  = l >> 4;
  const int row0 = blockIdx.x * 64;
  const int bi   = row0 >> 12;
  const int seqb = row0 & (SEQ - 1);

  // ---- stage x tile (fp32 -> fp16) ----
#pragma unroll
  for (int j = 0; j < 16; ++j) {
    const int li = j * 256 + t;         // float4-units
    const int r = li >> 6, c4 = (li & 63) * 4;
    float4 v4 = *(const float4*)(x + (size_t)(row0 + r) * DMODEL + c4);
    half4v h = {(f16)v4.x, (f16)v4.y, (f16)v4.z, (f16)v4.w};
    *(half4v*)(xs + r * XSP + c4) = h;
  }
  stage_w(Wq, wql[0], 0, t);
  __syncthreads();

  f32x4 acc[12];
#pragma unroll
  for (int i = 0; i < 12; ++i) acc[i] = (f32x4){0.f, 0.f, 0.f, 0.f};

  for (int kk = 0; kk < 8; ++kk) {
    if (kk < 7) stage_w(Wq, wql[(kk + 1) & 1], kk + 1, t);
    const f16* wb = wql[kk & 1];
    const half8 xa = *(const half8*)(xs + (w * 16 + qr) * XSP + kk * 32 + 8 * g);
#pragma unroll
    for (int nt = 0; nt < 12; ++nt) {
      const half8 wf = *(const half8*)(wb + (nt * 16 + qr) * WQP + 8 * g);
      if (nt < 8) acc[nt] = __builtin_amdgcn_mfma_f32_16x16x32_f16(wf, xa, acc[nt], 0, 0, 0);
      else        acc[nt] = __builtin_amdgcn_mfma_f32_16x16x32_f16(xa, wf, acc[nt], 0, 0, 0);
    }
    __syncthreads();
  }

  // ---- epilogue: bias, q-scale, fp16 stores ----
  const size_t grow = (size_t)row0 + w * 16 + qr;   // global row (q/k paths)
#pragma unroll
  for (int nt = 0; nt < 4; ++nt) {                  // q: D[d=4g+r][seq=qr]
    float4 b4 = *(const float4*)(bq + nt * 16 + 4 * g);
    half4v hv = {(f16)((acc[nt][0] + b4.x) * 0.125f),
                 (f16)((acc[nt][1] + b4.y) * 0.125f),
                 (f16)((acc[nt][2] + b4.z) * 0.125f),
                 (f16)((acc[nt][3] + b4.w) * 0.125f)};
    *(half4v*)(qh + grow * DHEAD + nt * 16 + 4 * g) = hv;
  }
#pragma unroll
  for (int nt = 4; nt < 8; ++nt) {                  // k
    float4 b4 = *(const float4*)(bq + 64 + (nt - 4) * 16 + 4 * g);
    half4v hv = {(f16)(acc[nt][0] + b4.x), (f16)(acc[nt][1] + b4.y),
                 (f16)(acc[nt][2] + b4.z), (f16)(acc[nt][3] + b4.w)};
    *(half4v*)(kh + grow * DHEAD + (nt - 4) * 16 + 4 * g) = hv;
  }
#pragma unroll
  for (int nt = 8; nt < 12; ++nt) {                 // v: D[seq=4g+r][d=qr]
    const int d = (nt - 8) * 16 + qr;
    const float bv = bq[128 + d];
    half4v hv = {(f16)(acc[nt][0] + bv), (f16)(acc[nt][1] + bv),
                 (f16)(acc[nt][2] + bv), (f16)(acc[nt][3] + bv)};
    *(half4v*)(vt + (size_t)bi * DHEAD * SEQ + (size_t)d * SEQ
               + seqb + w * 16 + 4 * g) = hv;
  }
  // ---- tail: blocks 0..15 emit W_out^T fp16 (wt[c][k]) ----
  if (blockIdx.x < 16) {
    const int gid = blockIdx.x * 256 + t;   // 0..4095
    const int c = gid & 255;
    const int k0 = (gid >> 8) * 4;          // 0..60
    half4v wv = {(f16)Wo[(size_t)(k0 + 0) * DMODEL + c],
                 (f16)Wo[(size_t)(k0 + 1) * DMODEL + c],
                 (f16)Wo[(size_t)(k0 + 2) * DMODEL + c],
                 (f16)Wo[(size_t)(k0 + 3) * DMODEL + c]};
    *(half4v*)(wt + (size_t)c * DHEAD + k0) = wv;
  }
}

// ---------------------------------------------------------------------------
// Kernel B: fused scores -> threshold -> masked softmax -> PV -> OUT PROJ.
// Byte-identical to R13 (verified): R7 async template + MFMA out-proj.
// ---------------------------------------------------------------------------
#define WAVES  8
#define CHUNK  32
#define NCHUNK 16
#define BUFH   2048    // halves per buffer (4 KB = 32 rows x 64 halves)

__device__ __forceinline__ int khash(int row) {   // bijective per permuted tile
  return ((row >> 2) & 6) | ((row >> 1) & 1);
}

typedef __attribute__((address_space(3))) f16 as3_f16;
typedef __attribute__((address_space(1))) const f16 as1_f16;

__device__ __forceinline__ void gll16(const f16* g, f16* l) {
  __builtin_amdgcn_global_load_lds((as1_f16*)g, (as3_f16*)l, 16, 0, 0);
}

#define SCHED_PIN __builtin_amdgcn_sched_barrier(0)
#define WAITVM4 do { asm volatile("s_waitcnt vmcnt(4)" ::: "memory"); \
                     __builtin_amdgcn_sched_barrier(0); } while (0)
#define WAITVM0 do { asm volatile("s_waitcnt vmcnt(0)" ::: "memory"); \
                     __builtin_amdgcn_sched_barrier(0); } while (0)

// K chunk -> LDS[row 0..31][slot 0..7], source slot pre-XOR'd with khash(row)
__device__ __forceinline__ void stage_k(const f16* kchunk, f16* buf, int l) {
#pragma unroll
  for (int i = 0; i < 4; ++i) {
    const int row = i * 8 + (l >> 3);
    const int c8 = (l & 7) ^ khash(row);
    gll16(kchunk + row * DHEAD + c8 * 8, buf + i * 512);
  }
}

// V chunk -> LDS rows = d&31 (128 B), slots 0..3 = d<32, 4..7 = d>=32, XOR r&7
__device__ __forceinline__ void stage_v(const f16* vchunk, f16* buf, int l) {
#pragma unroll
  for (int i = 0; i < 4; ++i) {
    const int r = i * 8 + (l >> 3);
    const int jj = (l & 7) ^ (r & 7);
    const int d = ((jj >> 2) << 5) + r;
    const int kb = jj & 3;
    gll16(vchunk + (size_t)d * SEQ + kb * 8, buf + i * 512);
  }
}

__global__ __launch_bounds__(512) void attn_fused(
    const f16* __restrict__ qh, const f16* __restrict__ kh,
    const f16* __restrict__ vt, const f16* __restrict__ wt,
    const float* __restrict__ bo, float* __restrict__ out)
{
  __shared__ f16 stage[WAVES][2 * BUFH];     // 64 KB: per-wave double buffer
  __shared__ float selbuf[2][WAVES][16];
  __shared__ float zrow[16];
  __shared__ float obuf[16 * 68];            // 4.35 KB: O rows (post-division)

  const int tid = threadIdx.x;
  const int w = tid >> 6;
  const int l = tid & 63;
  const int qr = l & 15;
  const int g  = l >> 4;
  const int bi = blockIdx.x >> 8;
  const int rb = blockIdx.x & 255;
  const size_t qrow0  = (size_t)bi * SEQ + (size_t)rb * 16;
  const size_t kvbase = (size_t)bi * SEQ * DHEAD;
  const int key0 = w * (CHUNK * NCHUNK);

  f16* const mybuf = &stage[w][0];

  // Q fragments (B operand), q pre-scaled by 1/8 in qh.
  half8 qf0, qf1;
  {
    const f16* qp = qh + (qrow0 + qr) * DHEAD;
    qf0 = *(const half8*)(qp + 8 * g);
    qf1 = *(const half8*)(qp + 32 + 8 * g);
  }

  half4v P[2 * NCHUNK];   // P[2kc+kt][r] = S[qr][32kc + 8g + 4kt + r]
  float mn = 1e30f, mx = -1e30f;

  // ---- QK^T: async pipeline, no barriers ----
  const f16* kc0 = kh + kvbase + (size_t)key0 * DHEAD;
  stage_k(kc0, mybuf, l);
  stage_k(kc0 + 32 * DHEAD, mybuf + BUFH, l);
#pragma unroll
  for (int kc = 0; kc < NCHUNK; ++kc) {
    if (kc < NCHUNK - 1) { WAITVM4; } else { WAITVM0; }
    const f16* bufp = mybuf + (kc & 1) * BUFH;
#pragma unroll
    for (int kt = 0; kt < 2; ++kt) {
      const int rowk = 8 * (qr >> 2) + 4 * kt + (qr & 3);   // permuted key row
      const int h = khash(rowk);
      f32x4 c = {0.f, 0.f, 0.f, 0.f};
      half8 kf0 = *(const half8*)(bufp + rowk * DHEAD + ((g ^ h) * 8));
      c = __builtin_amdgcn_mfma_f32_16x16x32_f16(kf0, qf0, c, 0, 0, 0);
      half8 kf1 = *(const half8*)(bufp + rowk * DHEAD + (((4 + g) ^ h) * 8));
      c = __builtin_amdgcn_mfma_f32_16x16x32_f16(kf1, qf1, c, 0, 0, 0);
      mn = fminf(mn, fminf(fminf(c[0], c[1]), fminf(c[2], c[3])));
      mx = fmaxf(mx, fmaxf(fmaxf(c[0], c[1]), fmaxf(c[2], c[3])));
      P[kc * 2 + kt] = (half4v){(f16)c[0], (f16)c[1], (f16)c[2], (f16)c[3]};
    }
    if (kc + 2 < NCHUNK) {
      SCHED_PIN;   // all reads of buf[kc&1] complete (in-order DS) before DMA
      stage_k(kc0 + (size_t)(kc + 2) * 32 * DHEAD, mybuf + (kc & 1) * BUFH, l);
    }
  }

  // ---- per-row min/max across lanes and waves ----
  mn = fminf(mn, __shfl_xor(mn, 16, 64));
  mn = fminf(mn, __shfl_xor(mn, 32, 64));
  mx = fmaxf(mx, __shfl_xor(mx, 16, 64));
  mx = fmaxf(mx, __shfl_xor(mx, 32, 64));
  if (l < 16) { selbuf[0][w][l] = mn; selbuf[1][w][l] = mx; }
  __syncthreads();
  float lo = 1e30f, hi = -1e30f;
#pragma unroll
  for (int j = 0; j < WAVES; ++j) {
    lo = fminf(lo, selbuf[0][j][qr]);
    hi = fmaxf(hi, selbuf[1][j][qr]);
  }
  __syncthreads();   // lo/hi reads done before iter 0 overwrites selbuf[0]

  // ---- bisection on sampled count (1024 of 4096; target 512) ----
#pragma unroll
  for (int it = 0; it < 10; ++it) {
    const float tm = 0.5f * (lo + hi);
    const f16 th = (f16)tm;
    int cnt = 0;
#pragma unroll
    for (int j = 0; j < 2 * NCHUNK; j += 4) {
      half4v s = P[j];
      cnt += (s[0] >= th) + (s[1] >= th) + (s[2] >= th) + (s[3] >= th);
    }
    cnt += __shfl_xor(cnt, 16, 64);
    cnt += __shfl_xor(cnt, 32, 64);
    if (l < 16) selbuf[it & 1][w][l] = (float)cnt;
    __syncthreads();
    float tot = 0.f;
#pragma unroll
    for (int j = 0; j < WAVES; ++j) tot += selbuf[it & 1][j][qr];
    if (tot >= 512.f) lo = tm; else hi = tm;
  }
  const float thr = lo;

  // ---- prefetch V chunks 0/1 (exp loop + z-barrier hide the latency) ----
  const f16* vchunk0 = vt + (size_t)bi * DHEAD * SEQ + key0;
  stage_v(vchunk0, mybuf, l);
  stage_v(vchunk0 + 32, mybuf + BUFH, l);

  // ---- exp in place (masked -> exp(0)=1, matches softmax(scores*mask)) ----
  float z = 0.f;
#pragma unroll
  for (int j = 0; j < 2 * NCHUNK; ++j) {
    half4v s = P[j];
    float p0 = (float)s[0], p1 = (float)s[1], p2 = (float)s[2], p3 = (float)s[3];
    p0 = (p0 >= thr) ? __expf(p0) : 1.f;
    p1 = (p1 >= thr) ? __expf(p1) : 1.f;
    p2 = (p2 >= thr) ? __expf(p2) : 1.f;
    p3 = (p3 >= thr) ? __expf(p3) : 1.f;
    z += (p0 + p1) + (p2 + p3);
    P[j] = (half4v){(f16)p0, (f16)p1, (f16)p2, (f16)p3};
  }
  z += __shfl_xor(z, 16, 64);
  z += __shfl_xor(z, 32, 64);
  if (l < 16) selbuf[0][w][l] = z;
  __syncthreads();
  if (w == 0 && l < 16) {
    float t2 = 0.f;
#pragma unroll
    for (int j = 0; j < WAVES; ++j) t2 += selbuf[0][j][l];
    zrow[l] = t2;   // consumed after the post-PV barrier
  }

  // ---- PV: O^T = V^T P^T; A = V^T (b128 LDS reads), B = P register concat ----
  f32x4 acc[4];
#pragma unroll
  for (int p = 0; p < 4; ++p) acc[p] = (f32x4){0.f, 0.f, 0.f, 0.f};

#pragma unroll
  for (int kc = 0; kc < NCHUNK; ++kc) {
    if (kc < NCHUNK - 1) { WAITVM4; } else { WAITVM0; }
    const f16* bufp = mybuf + (kc & 1) * BUFH;
    const half8 pb = __builtin_shufflevector(P[kc * 2], P[kc * 2 + 1],
                                             0, 1, 2, 3, 4, 5, 6, 7);
#pragma unroll
    for (int pnl = 0; pnl < 4; ++pnl) {
      const int d = 16 * pnl + qr;
      const int r = d & 31;
      const int j = (((d >> 5) << 2) + g) ^ (r & 7);
      half8 va = *(const half8*)(bufp + r * 64 + j * 8);
      acc[pnl] = __builtin_amdgcn_mfma_f32_16x16x32_f16(va, pb, acc[pnl], 0, 0, 0);
    }
    if (kc + 2 < NCHUNK) {
      SCHED_PIN;   // all reads of buf[kc&1] complete (in-order DS) before DMA
      stage_v(vchunk0 + (kc + 2) * 32, mybuf + (kc & 1) * BUFH, l);
    }
  }

  // ---- cross-wave reduce -> obuf (O/z), 68-pad rows ----
  float* red = (float*)mybuf;   // 16 rows x 68 floats = 4352 B per wave region
#pragma unroll
  for (int pnl = 0; pnl < 4; ++pnl)
    *(f32x4*)&red[qr * 68 + pnl * 16 + 4 * g] = acc[pnl];
  __syncthreads();
#pragma unroll
  for (int oo = 0; oo < 2; ++oo) {
    const int o = tid * 2 + oo;
    const int i = o >> 6, n = o & 63;
    float s = 0.f;
#pragma unroll
    for (int j = 0; j < WAVES; ++j) s += ((const float*)&stage[j][0])[i * 68 + n];
    obuf[i * 68 + n] = s / zrow[i];
  }
  __syncthreads();   // red reads done (stage reusable); obuf visible to all

  // ---- stage wt (W^T fp16) into stage[0..32KB]: wave w -> rows 32w..32w+31,
  // LDS linear, source block pre-XOR'd with (c&7) ----
  f16* const wl = &stage[0][0];
#pragma unroll
  for (int i = 0; i < 4; ++i) {
    const int c = (w * 4 + i) * 8 + (l >> 3);
    const int blk = (l & 7) ^ (c & 7);
    gll16(wt + (size_t)c * DHEAD + blk * 8, wl + (w * 4 + i) * 512);
  }
  WAITVM0;   // wave-local: wave w reads only rows it staged

  // ---- out = O @ W^T + bo via MFMA: wave w owns col tiles nt = 2w, 2w+1 ----
  half4v ofr[4];
#pragma unroll
  for (int pnl = 0; pnl < 4; ++pnl) {
    f32x4 o4 = *(const f32x4*)&obuf[qr * 68 + pnl * 16 + 4 * g];
    ofr[pnl] = (half4v){(f16)o4[0], (f16)o4[1], (f16)o4[2], (f16)o4[3]};
  }
#pragma unroll
  for (int nt2 = 0; nt2 < 2; ++nt2) {
    const int nt = w * 2 + nt2;
    const int c = 16 * nt + qr;             // output column
    const float bv = bo[c];
    f32x4 ao = {bv, bv, bv, bv};
#pragma unroll
    for (int pnl = 0; pnl < 4; ++pnl) {
      const int blk = 2 * pnl + (g >> 1);   // k-block = (16pnl+4g)>>3
      half4v wf = *(const half4v*)(wl + c * DHEAD + ((blk ^ (c & 7)) * 8) + (g & 1) * 4);
      ao = __builtin_amdgcn_mfma_f32_16x16x16f16(ofr[pnl], wf, ao, 0, 0, 0);
    }
    float* op = out + (qrow0 + 4 * g) * DMODEL + c;
#pragma unroll
    for (int r = 0; r < 4; ++r) op[r * DMODEL] = ao[r];
  }
}

// ---------------------------------------------------------------------------
extern "C" void kernel_launch(void* const* d_in, const int* in_sizes, int n_in,
                              void* d_out, int out_size, void* d_ws, size_t ws_size,
                              hipStream_t stream)
{
  (void)in_sizes; (void)n_in; (void)out_size; (void)ws_size;
  const float* x  = (const float*)d_in[0];
  const float* Wq = (const float*)d_in[1];
  const float* bq = (const float*)d_in[2];
  const float* Wo = (const float*)d_in[3];
  const float* bo = (const float*)d_in[4];
  float* out = (float*)d_out;
  char* ws = (char*)d_ws;
  f16* qh = (f16*)(ws);                              // 2 MB
  f16* kh = (f16*)(ws + (size_t)(2 << 20));          // 2 MB
  f16* vt = (f16*)(ws + (size_t)(4 << 20));          // 2 MB (transposed V)
  f16* wt = (f16*)(ws + (size_t)(6 << 20));          // 32 KB (W_out^T fp16)

  hipLaunchKernelGGL(qkv_mfma,   dim3(256),  dim3(256), 0, stream, x, Wq, bq, Wo, qh, kh, vt, wt);
  hipLaunchKernelGGL(attn_fused, dim3(1024), dim3(512), 0, stream, qh, kh, vt, wt, bo, out);
}

// Round 15
// 100.637 us; speedup vs baseline: 1.5142x; 1.1182x over previous
//
#include <hip/hip_runtime.h>
#include <hip/hip_fp16.h>
#include <stdint.h>

typedef _Float16 f16;
typedef _Float16 half8  __attribute__((ext_vector_type(8)));
typedef _Float16 half4v __attribute__((ext_vector_type(4)));
typedef float    f32x4  __attribute__((ext_vector_type(4)));

#define NBATCH 4
#define SEQ    4096
#define DMODEL 256
#define DHEAD  64
#define NQKV   192
// q pre-scale: 1/sqrt(64) * log2(e) -> scores arrive in log2 domain; exp = exp2
#define QSCALE 0.180336880f

// ---------------------------------------------------------------------------
// Kernel A (R14, verified): qkv via MFMA (fp16 in, fp32 acc). R15: q pre-scale
// includes log2(e) so attn uses exp2 directly.
// ---------------------------------------------------------------------------
#define XSP 272
#define WQP 40

__device__ __forceinline__ void stage_w(const float* __restrict__ Wq,
                                        f16* dst, int kk, int t) {
#pragma unroll
  for (int uu = 0; uu < 3; ++uu) {
    const int u = uu * 256 + t;       // 0..767 16B-units
    const int n = u >> 2;             // 0..191
    const int kc8 = u & 3;
    const int k0 = kk * 32 + kc8 * 8;
    half8 hv;
#pragma unroll
    for (int e = 0; e < 8; ++e) hv[e] = (f16)Wq[(size_t)(k0 + e) * NQKV + n];
    *(half8*)(dst + n * WQP + kc8 * 8) = hv;
  }
}

__global__ __launch_bounds__(256) void qkv_mfma(
    const float* __restrict__ x, const float* __restrict__ Wq,
    const float* __restrict__ bq, const float* __restrict__ Wo,
    f16* __restrict__ qh, f16* __restrict__ kh, f16* __restrict__ vt,
    f16* __restrict__ wt)
{
  __shared__ f16 xs[64 * XSP];          // 34816 B
  __shared__ f16 wql[2][192 * WQP];     // 30720 B  (total 64 KB)
  const int t = threadIdx.x;
  const int w = t >> 6;
  const int l = t & 63;
  const int qr = l & 15;
  const int g  = l >> 4;
  const int row0 = blockIdx.x * 64;
  const int bi   = row0 >> 12;
  const int seqb = row0 & (SEQ - 1);

  // ---- stage x tile (fp32 -> fp16) ----
#pragma unroll
  for (int j = 0; j < 16; ++j) {
    const int li = j * 256 + t;         // float4-units
    const int r = li >> 6, c4 = (li & 63) * 4;
    float4 v4 = *(const float4*)(x + (size_t)(row0 + r) * DMODEL + c4);
    half4v h = {(f16)v4.x, (f16)v4.y, (f16)v4.z, (f16)v4.w};
    *(half4v*)(xs + r * XSP + c4) = h;
  }
  stage_w(Wq, wql[0], 0, t);
  __syncthreads();

  f32x4 acc[12];
#pragma unroll
  for (int i = 0; i < 12; ++i) acc[i] = (f32x4){0.f, 0.f, 0.f, 0.f};

  for (int kk = 0; kk < 8; ++kk) {
    if (kk < 7) stage_w(Wq, wql[(kk + 1) & 1], kk + 1, t);
    const f16* wb = wql[kk & 1];
    const half8 xa = *(const half8*)(xs + (w * 16 + qr) * XSP + kk * 32 + 8 * g);
#pragma unroll
    for (int nt = 0; nt < 12; ++nt) {
      const half8 wf = *(const half8*)(wb + (nt * 16 + qr) * WQP + 8 * g);
      if (nt < 8) acc[nt] = __builtin_amdgcn_mfma_f32_16x16x32_f16(wf, xa, acc[nt], 0, 0, 0);
      else        acc[nt] = __builtin_amdgcn_mfma_f32_16x16x32_f16(xa, wf, acc[nt], 0, 0, 0);
    }
    __syncthreads();
  }

  // ---- epilogue: bias, q-scale (incl. log2e), fp16 stores ----
  const size_t grow = (size_t)row0 + w * 16 + qr;   // global row (q/k paths)
#pragma unroll
  for (int nt = 0; nt < 4; ++nt) {                  // q: D[d=4g+r][seq=qr]
    float4 b4 = *(const float4*)(bq + nt * 16 + 4 * g);
    half4v hv = {(f16)((acc[nt][0] + b4.x) * QSCALE),
                 (f16)((acc[nt][1] + b4.y) * QSCALE),
                 (f16)((acc[nt][2] + b4.z) * QSCALE),
                 (f16)((acc[nt][3] + b4.w) * QSCALE)};
    *(half4v*)(qh + grow * DHEAD + nt * 16 + 4 * g) = hv;
  }
#pragma unroll
  for (int nt = 4; nt < 8; ++nt) {                  // k
    float4 b4 = *(const float4*)(bq + 64 + (nt - 4) * 16 + 4 * g);
    half4v hv = {(f16)(acc[nt][0] + b4.x), (f16)(acc[nt][1] + b4.y),
                 (f16)(acc[nt][2] + b4.z), (f16)(acc[nt][3] + b4.w)};
    *(half4v*)(kh + grow * DHEAD + (nt - 4) * 16 + 4 * g) = hv;
  }
#pragma unroll
  for (int nt = 8; nt < 12; ++nt) {                 // v: D[seq=4g+r][d=qr]
    const int d = (nt - 8) * 16 + qr;
    const float bv = bq[128 + d];
    half4v hv = {(f16)(acc[nt][0] + bv), (f16)(acc[nt][1] + bv),
                 (f16)(acc[nt][2] + bv), (f16)(acc[nt][3] + bv)};
    *(half4v*)(vt + (size_t)bi * DHEAD * SEQ + (size_t)d * SEQ
               + seqb + w * 16 + 4 * g) = hv;
  }
  // ---- tail: blocks 0..15 emit W_out^T fp16 (wt[c][k]) ----
  if (blockIdx.x < 16) {
    const int gid = blockIdx.x * 256 + t;   // 0..4095
    const int c = gid & 255;
    const int k0 = (gid >> 8) * 4;          // 0..60
    half4v wv = {(f16)Wo[(size_t)(k0 + 0) * DMODEL + c],
                 (f16)Wo[(size_t)(k0 + 1) * DMODEL + c],
                 (f16)Wo[(size_t)(k0 + 2) * DMODEL + c],
                 (f16)Wo[(size_t)(k0 + 3) * DMODEL + c]};
    *(half4v*)(wt + (size_t)c * DHEAD + k0) = wv;
  }
}

// ---------------------------------------------------------------------------
// Kernel B: fused scores -> threshold -> masked softmax -> PV -> OUT PROJ.
// R15 change: WAVE-LOCAL selection — each wave thresholds its own 512 keys
// (shfl-only min/max + shfl-only bisection, target 64 of 128 samples).
// Removes 12 of ~14 barriers. exp via exp2f (log2e folded into q scale).
// QK^T/PV async loops + MFMA out-proj byte-identical to R13/R14 (verified).
// ---------------------------------------------------------------------------
#define WAVES  8
#define CHUNK  32
#define NCHUNK 16
#define BUFH   2048    // halves per buffer (4 KB = 32 rows x 64 halves)

__device__ __forceinline__ int khash(int row) {   // bijective per permuted tile
  return ((row >> 2) & 6) | ((row >> 1) & 1);
}

typedef __attribute__((address_space(3))) f16 as3_f16;
typedef __attribute__((address_space(1))) const f16 as1_f16;

__device__ __forceinline__ void gll16(const f16* g, f16* l) {
  __builtin_amdgcn_global_load_lds((as1_f16*)g, (as3_f16*)l, 16, 0, 0);
}

#define SCHED_PIN __builtin_amdgcn_sched_barrier(0)
#define WAITVM4 do { asm volatile("s_waitcnt vmcnt(4)" ::: "memory"); \
                     __builtin_amdgcn_sched_barrier(0); } while (0)
#define WAITVM0 do { asm volatile("s_waitcnt vmcnt(0)" ::: "memory"); \
                     __builtin_amdgcn_sched_barrier(0); } while (0)

// K chunk -> LDS[row 0..31][slot 0..7], source slot pre-XOR'd with khash(row)
__device__ __forceinline__ void stage_k(const f16* kchunk, f16* buf, int l) {
#pragma unroll
  for (int i = 0; i < 4; ++i) {
    const int row = i * 8 + (l >> 3);
    const int c8 = (l & 7) ^ khash(row);
    gll16(kchunk + row * DHEAD + c8 * 8, buf + i * 512);
  }
}

// V chunk -> LDS rows = d&31 (128 B), slots 0..3 = d<32, 4..7 = d>=32, XOR r&7
__device__ __forceinline__ void stage_v(const f16* vchunk, f16* buf, int l) {
#pragma unroll
  for (int i = 0; i < 4; ++i) {
    const int r = i * 8 + (l >> 3);
    const int jj = (l & 7) ^ (r & 7);
    const int d = ((jj >> 2) << 5) + r;
    const int kb = jj & 3;
    gll16(vchunk + (size_t)d * SEQ + kb * 8, buf + i * 512);
  }
}

__global__ __launch_bounds__(512) void attn_fused(
    const f16* __restrict__ qh, const f16* __restrict__ kh,
    const f16* __restrict__ vt, const f16* __restrict__ wt,
    const float* __restrict__ bo, float* __restrict__ out)
{
  __shared__ f16 stage[WAVES][2 * BUFH];     // 64 KB: per-wave double buffer
  __shared__ float selbuf[WAVES][16];        // z cross-wave reduce only
  __shared__ float zrow[16];
  __shared__ float obuf[16 * 68];            // 4.35 KB: O rows (post-division)

  const int tid = threadIdx.x;
  const int w = tid >> 6;
  const int l = tid & 63;
  const int qr = l & 15;
  const int g  = l >> 4;
  const int bi = blockIdx.x >> 8;
  const int rb = blockIdx.x & 255;
  const size_t qrow0  = (size_t)bi * SEQ + (size_t)rb * 16;
  const size_t kvbase = (size_t)bi * SEQ * DHEAD;
  const int key0 = w * (CHUNK * NCHUNK);

  f16* const mybuf = &stage[w][0];

  // Q fragments (B operand), q pre-scaled by QSCALE in qh.
  half8 qf0, qf1;
  {
    const f16* qp = qh + (qrow0 + qr) * DHEAD;
    qf0 = *(const half8*)(qp + 8 * g);
    qf1 = *(const half8*)(qp + 32 + 8 * g);
  }

  half4v P[2 * NCHUNK];   // P[2kc+kt][r] = S[qr][32kc + 8g + 4kt + r] (log2 dom.)
  float mn = 1e30f, mx = -1e30f;

  // ---- QK^T: async pipeline, no barriers ----
  const f16* kc0 = kh + kvbase + (size_t)key0 * DHEAD;
  stage_k(kc0, mybuf, l);
  stage_k(kc0 + 32 * DHEAD, mybuf + BUFH, l);
#pragma unroll
  for (int kc = 0; kc < NCHUNK; ++kc) {
    if (kc < NCHUNK - 1) { WAITVM4; } else { WAITVM0; }
    const f16* bufp = mybuf + (kc & 1) * BUFH;
#pragma unroll
    for (int kt = 0; kt < 2; ++kt) {
      const int rowk = 8 * (qr >> 2) + 4 * kt + (qr & 3);   // permuted key row
      const int h = khash(rowk);
      f32x4 c = {0.f, 0.f, 0.f, 0.f};
      half8 kf0 = *(const half8*)(bufp + rowk * DHEAD + ((g ^ h) * 8));
      c = __builtin_amdgcn_mfma_f32_16x16x32_f16(kf0, qf0, c, 0, 0, 0);
      half8 kf1 = *(const half8*)(bufp + rowk * DHEAD + (((4 + g) ^ h) * 8));
      c = __builtin_amdgcn_mfma_f32_16x16x32_f16(kf1, qf1, c, 0, 0, 0);
      mn = fminf(mn, fminf(fminf(c[0], c[1]), fminf(c[2], c[3])));
      mx = fmaxf(mx, fmaxf(fmaxf(c[0], c[1]), fmaxf(c[2], c[3])));
      P[kc * 2 + kt] = (half4v){(f16)c[0], (f16)c[1], (f16)c[2], (f16)c[3]};
    }
    if (kc + 2 < NCHUNK) {
      SCHED_PIN;   // all reads of buf[kc&1] complete (in-order DS) before DMA
      stage_k(kc0 + (size_t)(kc + 2) * 32 * DHEAD, mybuf + (kc & 1) * BUFH, l);
    }
  }

  // ---- WAVE-LOCAL selection: row min/max across the row's 4 lanes ----
  mn = fminf(mn, __shfl_xor(mn, 16, 64));
  mn = fminf(mn, __shfl_xor(mn, 32, 64));
  mx = fmaxf(mx, __shfl_xor(mx, 16, 64));
  mx = fmaxf(mx, __shfl_xor(mx, 32, 64));
  float lo = mn, hi = mx;

  // ---- wave-local bisection: 128 samples/row (32/lane), target 64 ----
#pragma unroll
  for (int it = 0; it < 10; ++it) {
    const float tm = 0.5f * (lo + hi);
    const f16 th = (f16)tm;
    int cnt = 0;
#pragma unroll
    for (int j = 0; j < 2 * NCHUNK; j += 4) {
      half4v s = P[j];
      cnt += (s[0] >= th) + (s[1] >= th) + (s[2] >= th) + (s[3] >= th);
    }
    cnt += __shfl_xor(cnt, 16, 64);
    cnt += __shfl_xor(cnt, 32, 64);
    if (cnt >= 64) lo = tm; else hi = tm;
  }
  const float thr = lo;

  // ---- prefetch V chunks 0/1 (exp loop hides the latency). SCHED_PIN keeps
  // the DMA issue below the last K-chunk's ds_reads (no barrier here now) ----
  SCHED_PIN;
  const f16* vchunk0 = vt + (size_t)bi * DHEAD * SEQ + key0;
  stage_v(vchunk0, mybuf, l);
  stage_v(vchunk0 + 32, mybuf + BUFH, l);

  // ---- exp2 in place (scores already in log2 domain; masked -> 1) ----
  float z = 0.f;
#pragma unroll
  for (int j = 0; j < 2 * NCHUNK; ++j) {
    half4v s = P[j];
    float p0 = (float)s[0], p1 = (float)s[1], p2 = (float)s[2], p3 = (float)s[3];
    p0 = (p0 >= thr) ? exp2f(p0) : 1.f;
    p1 = (p1 >= thr) ? exp2f(p1) : 1.f;
    p2 = (p2 >= thr) ? exp2f(p2) : 1.f;
    p3 = (p3 >= thr) ? exp2f(p3) : 1.f;
    z += (p0 + p1) + (p2 + p3);
    P[j] = (half4v){(f16)p0, (f16)p1, (f16)p2, (f16)p3};
  }
  z += __shfl_xor(z, 16, 64);
  z += __shfl_xor(z, 32, 64);
  if (l < 16) selbuf[w][l] = z;
  __syncthreads();
  if (w == 0 && l < 16) {
    float t2 = 0.f;
#pragma unroll
    for (int j = 0; j < WAVES; ++j) t2 += selbuf[j][l];
    zrow[l] = t2;   // consumed after the post-PV barrier
  }

  // ---- PV: O^T = V^T P^T; A = V^T (b128 LDS reads), B = P register concat ----
  f32x4 acc[4];
#pragma unroll
  for (int p = 0; p < 4; ++p) acc[p] = (f32x4){0.f, 0.f, 0.f, 0.f};

#pragma unroll
  for (int kc = 0; kc < NCHUNK; ++kc) {
    if (kc < NCHUNK - 1) { WAITVM4; } else { WAITVM0; }
    const f16* bufp = mybuf + (kc & 1) * BUFH;
    const half8 pb = __builtin_shufflevector(P[kc * 2], P[kc * 2 + 1],
                                             0, 1, 2, 3, 4, 5, 6, 7);
#pragma unroll
    for (int pnl = 0; pnl < 4; ++pnl) {
      const int d = 16 * pnl + qr;
      const int r = d & 31;
      const int j = (((d >> 5) << 2) + g) ^ (r & 7);
      half8 va = *(const half8*)(bufp + r * 64 + j * 8);
      acc[pnl] = __builtin_amdgcn_mfma_f32_16x16x32_f16(va, pb, acc[pnl], 0, 0, 0);
    }
    if (kc + 2 < NCHUNK) {
      SCHED_PIN;   // all reads of buf[kc&1] complete (in-order DS) before DMA
      stage_v(vchunk0 + (kc + 2) * 32, mybuf + (kc & 1) * BUFH, l);
    }
  }

  // ---- cross-wave reduce -> obuf (O/z), 68-pad rows ----
  float* red = (float*)mybuf;   // 16 rows x 68 floats = 4352 B per wave region
#pragma unroll
  for (int pnl = 0; pnl < 4; ++pnl)
    *(f32x4*)&red[qr * 68 + pnl * 16 + 4 * g] = acc[pnl];
  __syncthreads();
#pragma unroll
  for (int oo = 0; oo < 2; ++oo) {
    const int o = tid * 2 + oo;
    const int i = o >> 6, n = o & 63;
    float s = 0.f;
#pragma unroll
    for (int j = 0; j < WAVES; ++j) s += ((const float*)&stage[j][0])[i * 68 + n];
    obuf[i * 68 + n] = s / zrow[i];
  }
  __syncthreads();   // red reads done (stage reusable); obuf visible to all

  // ---- stage wt (W^T fp16) into stage[0..32KB]: wave w -> rows 32w..32w+31,
  // LDS linear, source block pre-XOR'd with (c&7) ----
  f16* const wl = &stage[0][0];
#pragma unroll
  for (int i = 0; i < 4; ++i) {
    const int c = (w * 4 + i) * 8 + (l >> 3);
    const int blk = (l & 7) ^ (c & 7);
    gll16(wt + (size_t)c * DHEAD + blk * 8, wl + (w * 4 + i) * 512);
  }
  WAITVM0;   // wave-local: wave w reads only rows it staged

  // ---- out = O @ W^T + bo via MFMA: wave w owns col tiles nt = 2w, 2w+1 ----
  half4v ofr[4];
#pragma unroll
  for (int pnl = 0; pnl < 4; ++pnl) {
    f32x4 o4 = *(const f32x4*)&obuf[qr * 68 + pnl * 16 + 4 * g];
    ofr[pnl] = (half4v){(f16)o4[0], (f16)o4[1], (f16)o4[2], (f16)o4[3]};
  }
#pragma unroll
  for (int nt2 = 0; nt2 < 2; ++nt2) {
    const int nt = w * 2 + nt2;
    const int c = 16 * nt + qr;             // output column
    const float bv = bo[c];
    f32x4 ao = {bv, bv, bv, bv};
#pragma unroll
    for (int pnl = 0; pnl < 4; ++pnl) {
      const int blk = 2 * pnl + (g >> 1);   // k-block = (16pnl+4g)>>3
      half4v wf = *(const half4v*)(wl + c * DHEAD + ((blk ^ (c & 7)) * 8) + (g & 1) * 4);
      ao = __builtin_amdgcn_mfma_f32_16x16x16f16(ofr[pnl], wf, ao, 0, 0, 0);
    }
    float* op = out + (qrow0 + 4 * g) * DMODEL + c;
#pragma unroll
    for (int r = 0; r < 4; ++r) op[r * DMODEL] = ao[r];
  }
}

// ---------------------------------------------------------------------------
extern "C" void kernel_launch(void* const* d_in, const int* in_sizes, int n_in,
                              void* d_out, int out_size, void* d_ws, size_t ws_size,
                              hipStream_t stream)
{
  (void)in_sizes; (void)n_in; (void)out_size; (void)ws_size;
  const float* x  = (const float*)d_in[0];
  const float* Wq = (const float*)d_in[1];
  const float* bq = (const float*)d_in[2];
  const float* Wo = (const float*)d_in[3];
  const float* bo = (const float*)d_in[4];
  float* out = (float*)d_out;
  char* ws = (char*)d_ws;
  f16* qh = (f16*)(ws);                              // 2 MB
  f16* kh = (f16*)(ws + (size_t)(2 << 20));          // 2 MB
  f16* vt = (f16*)(ws + (size_t)(4 << 20));          // 2 MB (transposed V)
  f16* wt = (f16*)(ws + (size_t)(6 << 20));          // 32 KB (W_out^T fp16)

  hipLaunchKernelGGL(qkv_mfma,   dim3(256),  dim3(256), 0, stream, x, Wq, bq, Wo, qh, kh, vt, wt);
  hipLaunchKernelGGL(attn_fused, dim3(1024), dim3(512), 0, stream, qh, kh, vt, wt, bo, out);
}